// Round 10
// baseline (3223.523 us; speedup 1.0000x reference)
//
#include <hip/hip_runtime.h>

typedef unsigned short u16;
typedef unsigned int   u32;
typedef unsigned long long u64;
typedef __attribute__((ext_vector_type(8)))  short  short8v;   // 8 x bf16 (as i16)
typedef __attribute__((ext_vector_type(4)))  float  f32x4;
typedef __attribute__((ext_vector_type(16))) float  f32x16;
typedef __attribute__((ext_vector_type(4)))  unsigned short ushort4v;
typedef __attribute__((ext_vector_type(4)))  u32 u32x4;

#define B_   32
#define T_   512
#define D_   1024
#define N4_  4096

// ---- workspace layout (bytes) ----
#define OFF_XN   0ull                 // xn bf16   [32*512*1024]      33554432
#define OFF_ZX   33554432ull          // Zx bf16   [512][32][1024][4] 134217728  (gate-interleaved)
#define OFF_KT   167772160ull         // kernel^T bf16 [4096][1024]    8388608  (reused as h_last after GEMM)
#define OFF_RT   176160768ull         // recurrent^T bf16 [4096][1024] 8388608
#define OFF_HB   184549376ull         // h double buffer bf16 2*[32][1024] = 131072 (tag-in-band)

__device__ inline u16 f2bf(float f) {
  union { float f; u32 u; } x; x.f = f;
  u32 r = x.u + 0x7FFFu + ((x.u >> 16) & 1u);   // RNE
  return (u16)(r >> 16);
}
__device__ inline float bf2f(u16 h) {
  union { u32 u; float f; } x; x.u = ((u32)h) << 16; return x.f;
}
__device__ inline float sigm(float x) { return 1.f / (1.f + __expf(-x)); }
__device__ inline float tanh_fast(float x) {
  float e = __expf(2.f * x);
  return 1.f - 2.f / (e + 1.f);
}

// ---------------- init: zero h buffers (tag bits = 0 -> step-0 data valid) ----------------
__global__ __launch_bounds__(256) void init_kernel(u32* hbuf) {
  int i = blockIdx.x * 256 + threadIdx.x;
  if (i < 32768) hbuf[i] = 0u;       // both parities: 2*32*1024 bf16
}

// ---------------- LN1: x fp32 -> xn bf16 ----------------
__global__ __launch_bounds__(256) void ln1_kernel(const float* __restrict__ x,
    const float* __restrict__ gam, const float* __restrict__ bet, u16* __restrict__ xn) {
  int row = blockIdx.x; int tid = threadIdx.x;
  const float* xr = x + (size_t)row * D_;
  float4 v = *(const float4*)(xr + tid * 4);
  float s  = v.x + v.y + v.z + v.w;
  float ss = v.x*v.x + v.y*v.y + v.z*v.z + v.w*v.w;
  #pragma unroll
  for (int o = 32; o > 0; o >>= 1) { s += __shfl_down(s, o); ss += __shfl_down(ss, o); }
  __shared__ float red[8];
  int w = tid >> 6, l = tid & 63;
  if (l == 0) { red[w] = s; red[4 + w] = ss; }
  __syncthreads();
  s  = red[0] + red[1] + red[2] + red[3];
  ss = red[4] + red[5] + red[6] + red[7];
  float mean = s * (1.f / D_);
  float var  = ss * (1.f / D_) - mean * mean;
  float rstd = rsqrtf(var + 1e-3f);
  float4 g = *(const float4*)(gam + tid * 4);
  float4 b = *(const float4*)(bet + tid * 4);
  ushort4v o4;
  o4.x = f2bf((v.x - mean) * rstd * g.x + b.x);
  o4.y = f2bf((v.y - mean) * rstd * g.y + b.y);
  o4.z = f2bf((v.z - mean) * rstd * g.z + b.z);
  o4.w = f2bf((v.w - mean) * rstd * g.w + b.w);
  *(ushort4v*)(xn + (size_t)row * D_ + tid * 4) = o4;
}

// ---------------- transpose [1024][4096] fp32 -> [4096][1024] bf16 ----------------
__global__ __launch_bounds__(256) void transpose_bf16(const float* __restrict__ W, u16* __restrict__ WT) {
  __shared__ float tile[32][33];
  int c0 = blockIdx.x * 32, r0 = blockIdx.y * 32;
  int tx = threadIdx.x, ty = threadIdx.y;
  #pragma unroll
  for (int i = ty; i < 32; i += 8)
    tile[i][tx] = W[(size_t)(r0 + i) * N4_ + c0 + tx];
  __syncthreads();
  #pragma unroll
  for (int i = ty; i < 32; i += 8)
    WT[(size_t)(c0 + i) * D_ + r0 + tx] = f2bf(tile[tx][i]);
}

// ---------------- GEMM: Zx = xn @ kernel + bias  (gate-interleaved output) ----------------
__global__ __launch_bounds__(256) void gemm_xk(const u16* __restrict__ A, const u16* __restrict__ Bt,
    const float* __restrict__ bias, u16* __restrict__ Zx) {
  __shared__ u16 As[128 * 32];
  __shared__ u16 Bs[128 * 32];
  int tid = threadIdx.x;
  int bm = blockIdx.x >> 5, bn = blockIdx.x & 31;
  int w = tid >> 6, l = tid & 63;
  int srow = tid >> 2, sk = (tid & 3) * 8;        // staging: row j*64+srow, k = sk..sk+8
  const u16* Ag = A  + (size_t)(bm * 128 + srow) * D_ + sk;
  const u16* Bg = Bt + (size_t)(bn * 128 + srow) * D_ + sk;
  int sb0 = (srow * 64 + sk * 2)          ^ ((srow & 3) << 4);
  int sb1 = ((srow + 64) * 64 + sk * 2)   ^ ((srow & 3) << 4);
  int wm = w >> 1, wn = w & 1;
  int frow = l & 15, fko = (l >> 4) * 16;         // fragment k byte offset
  f32x4 acc[4][4];
  #pragma unroll
  for (int mi = 0; mi < 4; ++mi)
    #pragma unroll
    for (int ni = 0; ni < 4; ++ni)
      #pragma unroll
      for (int j = 0; j < 4; ++j) acc[mi][ni][j] = 0.f;

  short8v ap0 = *(const short8v*)(Ag);
  short8v ap1 = *(const short8v*)(Ag + 64 * (size_t)D_);
  short8v bp0 = *(const short8v*)(Bg);
  short8v bp1 = *(const short8v*)(Bg + 64 * (size_t)D_);

  for (int kt = 0; kt < 32; ++kt) {
    __syncthreads();
    *(short8v*)((char*)As + sb0) = ap0;
    *(short8v*)((char*)As + sb1) = ap1;
    *(short8v*)((char*)Bs + sb0) = bp0;
    *(short8v*)((char*)Bs + sb1) = bp1;
    __syncthreads();
    if (kt < 31) {
      ap0 = *(const short8v*)(Ag + (kt + 1) * 32);
      ap1 = *(const short8v*)(Ag + 64 * (size_t)D_ + (kt + 1) * 32);
      bp0 = *(const short8v*)(Bg + (kt + 1) * 32);
      bp1 = *(const short8v*)(Bg + 64 * (size_t)D_ + (kt + 1) * 32);
    }
    short8v af[4], bfr[4];
    #pragma unroll
    for (int mi = 0; mi < 4; ++mi) {
      int r = wm * 64 + mi * 16 + frow;
      af[mi] = *(const short8v*)((char*)As + ((r * 64 + fko) ^ ((r & 3) << 4)));
    }
    #pragma unroll
    for (int ni = 0; ni < 4; ++ni) {
      int r = wn * 64 + ni * 16 + frow;
      bfr[ni] = *(const short8v*)((char*)Bs + ((r * 64 + fko) ^ ((r & 3) << 4)));
    }
    #pragma unroll
    for (int mi = 0; mi < 4; ++mi)
      #pragma unroll
      for (int ni = 0; ni < 4; ++ni)
        acc[mi][ni] = __builtin_amdgcn_mfma_f32_16x16x32_bf16(af[mi], bfr[ni], acc[mi][ni], 0, 0, 0);
  }
  // epilogue: +bias, bf16, remap rows to [t][b] and cols to [unit][gate]
  #pragma unroll
  for (int mi = 0; mi < 4; ++mi) {
    #pragma unroll
    for (int ni = 0; ni < 4; ++ni) {
      int col = bn * 128 + wn * 64 + ni * 16 + (l & 15);
      float bv = bias[col];
      int colp = ((col & 1023) << 2) | (col >> 10);   // gate-interleaved
      #pragma unroll
      for (int j = 0; j < 4; ++j) {
        int row = bm * 128 + wm * 64 + mi * 16 + (l >> 4) * 4 + j;
        int zrow = (row & 511) * 32 + (row >> 9);
        Zx[(size_t)zrow * N4_ + colp] = f2bf(acc[mi][ni][j] + bv);
      }
    }
  }
}

// ---------------- persistent LSTM scan ----------------
// 32 WGs x 1024 thr (16 waves = 4 K-splits x 4 gates). WG owns units [wg*32, wg*32+32).
// FLAGLESS exchange: |h|<1 guarantees bf16 bit14==0, so producers embed a 2-bit
// step tag ((t+1)&3) in bit14 of the lo/hi halves of each stored u32. Consumers
// poll THE DATA ITSELF (their own 64B slice, sc0/sc1 loads, re-issuing only
// unvalidated 16B lines) and mask tags off. One store->detect latency per step;
// no flag store, no flag RT, no publish barrier, no wave0 poll (R9 post-mortem:
// the 3-hop flag protocol was the whole 4us/step).
// Overwrite safety: WG reaching step t+2 polled ALL of t+1 => every WG finished
// reading t => double buffer slot (t&1) is dead. Mod-4 tag distinguishes t from t-2.
__global__ __launch_bounds__(1024)
void lstm_scan(const u16* __restrict__ Zx,
    const u16* __restrict__ RT, u16* hbuf, float* h_last) {
  __shared__ u16   h_lds[B_ * D_];           // 64 KB, XOR-swizzled rows
  __shared__ float z_lds[128 * 136];         // 69.6 KB: [ks*32+row][stride 136]
  int tid = threadIdx.x;
  int wg = blockIdx.x;
  int w = tid >> 6, l = tid & 63;
  int ks = w >> 2, cg = w & 3;               // K-range ks*256..+256, gate cg

  // preload B fragments (R^T): 16 kt (pin attempt; neutral either way per R6/R7/R9)
  short8v b[16];
  {
    const u16* Rp = RT + (size_t)(cg * 1024 + wg * 32 + (l & 31)) * D_
                  + ks * 256 + (l >> 5) * 8;
    #pragma unroll
    for (int kt = 0; kt < 16; ++kt) b[kt] = *(const short8v*)(Rp + kt * 16);
  }
  #pragma unroll
  for (int kt = 0; kt < 16; ++kt) asm volatile("" : "+v"(b[kt]));

  // A-fragment addressing (h in LDS, swizzled)
  int arow = l & 31;
  int abase = arow * 2048 + (ks * 256 + (l >> 5) * 8) * 2;
  int asw = (arow & 7) << 4;
  // gate cell: (grow, gu)
  int grow = tid >> 5, gu = tid & 31;
  const u16* zx_p = Zx + (size_t)grow * N4_ + (wg * 32 + gu) * 4;
  int hoff = grow * D_ + wg * 32 + gu;
  float c = 0.f;

  #pragma unroll 1
  for (int t = 0; t < T_; ++t) {
    // Zx prefetch (4 gate pre-activations, one 8B load) — overlaps the data poll
    u64 zq = *(const u64*)(zx_p + (size_t)t * B_ * N4_);
    __builtin_amdgcn_sched_barrier(0);

    // poll tagged h data directly: 4 x 16B per thread, re-issue only stale lines
    const char* hbp = (const char*)hbuf + (size_t)(t & 1) * 65536;
    u32 tg  = (u32)t & 3u;
    u32 pat = ((tg & 1u) << 14) | (((tg >> 1) & 1u) << 30);
    u32x4 hv0, hv1, hv2, hv3;
    u32 okm = 0u;
    const char* p0 = hbp + 0 * 16384 + tid * 16;
    const char* p1 = hbp + 1 * 16384 + tid * 16;
    const char* p2 = hbp + 2 * 16384 + tid * 16;
    const char* p3 = hbp + 3 * 16384 + tid * 16;
    while (okm != 0xFu) {
      if (!(okm & 1u)) asm volatile("global_load_dwordx4 %0, %1, off sc0 sc1" : "=&v"(hv0) : "v"(p0) : "memory");
      if (!(okm & 2u)) asm volatile("global_load_dwordx4 %0, %1, off sc0 sc1" : "=&v"(hv1) : "v"(p1) : "memory");
      if (!(okm & 4u)) asm volatile("global_load_dwordx4 %0, %1, off sc0 sc1" : "=&v"(hv2) : "v"(p2) : "memory");
      if (!(okm & 8u)) asm volatile("global_load_dwordx4 %0, %1, off sc0 sc1" : "=&v"(hv3) : "v"(p3) : "memory");
      asm volatile("s_waitcnt vmcnt(0)" ::: "memory");
      if (!(okm & 1u) && ((((hv0[0]^pat)|(hv0[1]^pat)|(hv0[2]^pat)|(hv0[3]^pat)) & 0x40004000u) == 0u)) okm |= 1u;
      if (!(okm & 2u) && ((((hv1[0]^pat)|(hv1[1]^pat)|(hv1[2]^pat)|(hv1[3]^pat)) & 0x40004000u) == 0u)) okm |= 2u;
      if (!(okm & 4u) && ((((hv2[0]^pat)|(hv2[1]^pat)|(hv2[2]^pat)|(hv2[3]^pat)) & 0x40004000u) == 0u)) okm |= 4u;
      if (!(okm & 8u) && ((((hv3[0]^pat)|(hv3[1]^pat)|(hv3[2]^pat)|(hv3[3]^pat)) & 0x40004000u) == 0u)) okm |= 8u;
    }
    // clear tag bits and stage into swizzled LDS
    {
      u32x4 vv[4] = { hv0, hv1, hv2, hv3 };
      #pragma unroll
      for (int j = 0; j < 4; ++j) {
        u32x4 v = vv[j];
        v[0] &= 0xBFFFBFFFu; v[1] &= 0xBFFFBFFFu; v[2] &= 0xBFFFBFFFu; v[3] &= 0xBFFFBFFFu;
        int byte = j * 16384 + tid * 16;
        int row = byte >> 11;
        *(u32x4*)((char*)h_lds + (byte ^ ((row & 7) << 4))) = v;
      }
    }
    __syncthreads();

    // K-loop: 16 x (ds_read_b128 + mfma 32x32x16)
    f32x16 acc;
    #pragma unroll
    for (int i = 0; i < 16; ++i) acc[i] = 0.f;
    #pragma unroll
    for (int kt = 0; kt < 16; ++kt) {
      short8v a = *(const short8v*)((const char*)h_lds + ((abase + kt * 32) ^ asw));
      acc = __builtin_amdgcn_mfma_f32_32x32x16_bf16(a, b[kt], acc, 0, 0, 0);
    }
    // write K-partials: D layout row=(r&3)+8*(r>>2)+4*(lane>>5), col=lane&31
    #pragma unroll
    for (int r = 0; r < 16; ++r) {
      int rowD = (r & 3) + 8 * (r >> 2) + 4 * (l >> 5);
      z_lds[(ks * 32 + rowD) * 136 + cg * 32 + (l & 31)] = acc[r];
    }
    __syncthreads();

    // gates: one cell per thread
    float z0 = bf2f((u16)(zq        & 0xFFFFu));
    float z1 = bf2f((u16)((zq >> 16) & 0xFFFFu));
    float z2 = bf2f((u16)((zq >> 32) & 0xFFFFu));
    float z3 = bf2f((u16)((zq >> 48) & 0xFFFFu));
    #pragma unroll
    for (int kss = 0; kss < 4; ++kss) {
      const float* zr = &z_lds[(kss * 32 + grow) * 136 + gu];
      z0 += zr[0]; z1 += zr[32]; z2 += zr[64]; z3 += zr[96];
    }
    float cn = sigm(z1) * c + sigm(z0) * tanh_fast(z2);
    float hn = sigm(z3) * tanh_fast(cn);
    c = cn;

    // publish tagged h word (pair lanes -> one u32 agent-scope store; fire & forget)
    u32 tgn = (u32)(t + 1) & 3u;
    u32 hw = (u32)f2bf(hn);
    if (hw & 0x4000u) hw = (hw & 0x8000u) | 0x3F7Fu;   // clamp |h|>=1.0 rounding (protect tag bit)
    u32 nb = __shfl_down(hw, 1);
    if (!(gu & 1)) {
      u32 word = (hw | ((tgn & 1u) << 14))
               | ((nb | (((tgn >> 1) & 1u) << 14)) << 16);
      u32* dst = (u32*)(hbuf + (size_t)((t + 1) & 1) * (B_ * D_) + hoff);
      __hip_atomic_store(dst, word, __ATOMIC_RELAXED, __HIP_MEMORY_SCOPE_AGENT);
    }
    if (t == T_ - 1) h_last[hoff] = hn;
    // no barrier, no flag: the tagged store is self-announcing
  }
}

// ---------------- LN2: out = LN(xn + h_last) fp32 ----------------
__global__ __launch_bounds__(256) void ln2_kernel(const u16* __restrict__ xn,
    const float* __restrict__ h_last, const float* __restrict__ gam,
    const float* __restrict__ bet, float* __restrict__ out) {
  int row = blockIdx.x; int tid = threadIdx.x;
  int bi = row >> 9;
  ushort4v xv = *(const ushort4v*)(xn + (size_t)row * D_ + tid * 4);
  float4 hv = *(const float4*)(h_last + (size_t)bi * D_ + tid * 4);
  float s0 = bf2f(xv.x) + hv.x;
  float s1 = bf2f(xv.y) + hv.y;
  float s2 = bf2f(xv.z) + hv.z;
  float s3 = bf2f(xv.w) + hv.w;
  float s = s0 + s1 + s2 + s3;
  float ss = s0*s0 + s1*s1 + s2*s2 + s3*s3;
  #pragma unroll
  for (int o = 32; o > 0; o >>= 1) { s += __shfl_down(s, o); ss += __shfl_down(ss, o); }
  __shared__ float red[8];
  int w = tid >> 6, l = tid & 63;
  if (l == 0) { red[w] = s; red[4 + w] = ss; }
  __syncthreads();
  s  = red[0] + red[1] + red[2] + red[3];
  ss = red[4] + red[5] + red[6] + red[7];
  float mean = s * (1.f / D_);
  float var  = ss * (1.f / D_) - mean * mean;
  float rstd = rsqrtf(var + 1e-3f);
  float4 g = *(const float4*)(gam + tid * 4);
  float4 b = *(const float4*)(bet + tid * 4);
  float4 o4;
  o4.x = (s0 - mean) * rstd * g.x + b.x;
  o4.y = (s1 - mean) * rstd * g.y + b.y;
  o4.z = (s2 - mean) * rstd * g.z + b.z;
  o4.w = (s3 - mean) * rstd * g.w + b.w;
  *(float4*)(out + (size_t)row * D_ + tid * 4) = o4;
}

extern "C" void kernel_launch(void* const* d_in, const int* in_sizes, int n_in,
                              void* d_out, int out_size, void* d_ws, size_t ws_size,
                              hipStream_t stream) {
  const float* x    = (const float*)d_in[0];
  const float* g1   = (const float*)d_in[1];
  const float* b1   = (const float*)d_in[2];
  const float* Wk   = (const float*)d_in[3];
  const float* Wr   = (const float*)d_in[4];
  const float* bias = (const float*)d_in[5];
  const float* g2   = (const float*)d_in[6];
  const float* b2   = (const float*)d_in[7];
  char* ws = (char*)d_ws;
  u16* xn    = (u16*)(ws + OFF_XN);
  u16* Zx    = (u16*)(ws + OFF_ZX);
  u16* KT    = (u16*)(ws + OFF_KT);
  u16* RT    = (u16*)(ws + OFF_RT);
  u16* hbuf  = (u16*)(ws + OFF_HB);
  float* hl  = (float*)(ws + OFF_KT);    // aliases KT (dead after gemm_xk)
  float* out = (float*)d_out;

  init_kernel<<<128, 256, 0, stream>>>((u32*)hbuf);
  ln1_kernel<<<B_ * T_, 256, 0, stream>>>(x, g1, b1, xn);
  transpose_bf16<<<dim3(128, 32), dim3(32, 8), 0, stream>>>(Wk, KT);
  transpose_bf16<<<dim3(128, 32), dim3(32, 8), 0, stream>>>(Wr, RT);
  gemm_xk<<<4096, 256, 0, stream>>>(xn, KT, bias, Zx);
  lstm_scan<<<32, 1024, 0, stream>>>(Zx, RT, hbuf, hl);
  ln2_kernel<<<B_ * T_, 256, 0, stream>>>(xn, hl, g2, b2, out);
}

// Round 11
// 2347.086 us; speedup vs baseline: 1.3734x; 1.3734x over previous
//
#include <hip/hip_runtime.h>

typedef unsigned short u16;
typedef unsigned int   u32;
typedef unsigned long long u64;
typedef __attribute__((ext_vector_type(8)))  short  short8v;   // 8 x bf16 (as i16)
typedef __attribute__((ext_vector_type(2)))  float  f32x2;
typedef __attribute__((ext_vector_type(4)))  float  f32x4;
typedef __attribute__((ext_vector_type(16))) float  f32x16;
typedef __attribute__((ext_vector_type(4)))  unsigned short ushort4v;
typedef __attribute__((ext_vector_type(4)))  u32 u32x4;

#define B_   32
#define T_   512
#define D_   1024
#define N4_  4096

// ---- workspace layout (bytes) ----
#define OFF_XN   0ull                 // xn bf16   [32*512*1024]      33554432
#define OFF_ZX   33554432ull          // Zx bf16   [512][32][1024][4] 134217728  (gate-interleaved)
#define OFF_KT   167772160ull         // kernel^T bf16 [4096][1024]    8388608  (reused as h_last after GEMM)
#define OFF_RT   176160768ull         // recurrent^T bf16 [4096][1024] 8388608
#define OFF_HB   184549376ull         // h double buffer bf16 2*[32][1024] = 131072
#define OFF_FLG  184680448ull         // flags: 32 x 64B-strided u32

__device__ inline u16 f2bf(float f) {
  union { float f; u32 u; } x; x.f = f;
  u32 r = x.u + 0x7FFFu + ((x.u >> 16) & 1u);   // RNE
  return (u16)(r >> 16);
}
__device__ inline float bf2f(u16 h) {
  union { u32 u; float f; } x; x.u = ((u32)h) << 16; return x.f;
}
__device__ inline float sigm(float x) { return 1.f / (1.f + __expf(-x)); }
__device__ inline float tanh_fast(float x) {
  float e = __expf(2.f * x);
  return 1.f - 2.f / (e + 1.f);
}

// ---------------- init: zero h buffers + flags ----------------
__global__ __launch_bounds__(256) void init_kernel(u32* hbuf, u32* flags) {
  int i = blockIdx.x * 256 + threadIdx.x;
  if (i < 32768) hbuf[i] = 0u;       // both parities: 2*32*1024 bf16 = 32768 dwords
  if (i < 32)    flags[i * 16] = 0u;
}

// ---------------- LN1: x fp32 -> xn bf16 ----------------
__global__ __launch_bounds__(256) void ln1_kernel(const float* __restrict__ x,
    const float* __restrict__ gam, const float* __restrict__ bet, u16* __restrict__ xn) {
  int row = blockIdx.x; int tid = threadIdx.x;
  const float* xr = x + (size_t)row * D_;
  float4 v = *(const float4*)(xr + tid * 4);
  float s  = v.x + v.y + v.z + v.w;
  float ss = v.x*v.x + v.y*v.y + v.z*v.z + v.w*v.w;
  #pragma unroll
  for (int o = 32; o > 0; o >>= 1) { s += __shfl_down(s, o); ss += __shfl_down(ss, o); }
  __shared__ float red[8];
  int w = tid >> 6, l = tid & 63;
  if (l == 0) { red[w] = s; red[4 + w] = ss; }
  __syncthreads();
  s  = red[0] + red[1] + red[2] + red[3];
  ss = red[4] + red[5] + red[6] + red[7];
  float mean = s * (1.f / D_);
  float var  = ss * (1.f / D_) - mean * mean;
  float rstd = rsqrtf(var + 1e-3f);
  float4 g = *(const float4*)(gam + tid * 4);
  float4 b = *(const float4*)(bet + tid * 4);
  ushort4v o4;
  o4.x = f2bf((v.x - mean) * rstd * g.x + b.x);
  o4.y = f2bf((v.y - mean) * rstd * g.y + b.y);
  o4.z = f2bf((v.z - mean) * rstd * g.z + b.z);
  o4.w = f2bf((v.w - mean) * rstd * g.w + b.w);
  *(ushort4v*)(xn + (size_t)row * D_ + tid * 4) = o4;
}

// ---------------- transpose [1024][4096] fp32 -> [4096][1024] bf16 ----------------
__global__ __launch_bounds__(256) void transpose_bf16(const float* __restrict__ W, u16* __restrict__ WT) {
  __shared__ float tile[32][33];
  int c0 = blockIdx.x * 32, r0 = blockIdx.y * 32;
  int tx = threadIdx.x, ty = threadIdx.y;
  #pragma unroll
  for (int i = ty; i < 32; i += 8)
    tile[i][tx] = W[(size_t)(r0 + i) * N4_ + c0 + tx];
  __syncthreads();
  #pragma unroll
  for (int i = ty; i < 32; i += 8)
    WT[(size_t)(c0 + i) * D_ + r0 + tx] = f2bf(tile[tx][i]);
}

// ---------------- GEMM: Zx = xn @ kernel + bias  (gate-interleaved output) ----------------
__global__ __launch_bounds__(256) void gemm_xk(const u16* __restrict__ A, const u16* __restrict__ Bt,
    const float* __restrict__ bias, u16* __restrict__ Zx) {
  __shared__ u16 As[128 * 32];
  __shared__ u16 Bs[128 * 32];
  int tid = threadIdx.x;
  int bm = blockIdx.x >> 5, bn = blockIdx.x & 31;
  int w = tid >> 6, l = tid & 63;
  int srow = tid >> 2, sk = (tid & 3) * 8;        // staging: row j*64+srow, k = sk..sk+8
  const u16* Ag = A  + (size_t)(bm * 128 + srow) * D_ + sk;
  const u16* Bg = Bt + (size_t)(bn * 128 + srow) * D_ + sk;
  int sb0 = (srow * 64 + sk * 2)          ^ ((srow & 3) << 4);
  int sb1 = ((srow + 64) * 64 + sk * 2)   ^ ((srow & 3) << 4);
  int wm = w >> 1, wn = w & 1;
  int frow = l & 15, fko = (l >> 4) * 16;         // fragment k byte offset
  f32x4 acc[4][4];
  #pragma unroll
  for (int mi = 0; mi < 4; ++mi)
    #pragma unroll
    for (int ni = 0; ni < 4; ++ni)
      #pragma unroll
      for (int j = 0; j < 4; ++j) acc[mi][ni][j] = 0.f;

  short8v ap0 = *(const short8v*)(Ag);
  short8v ap1 = *(const short8v*)(Ag + 64 * (size_t)D_);
  short8v bp0 = *(const short8v*)(Bg);
  short8v bp1 = *(const short8v*)(Bg + 64 * (size_t)D_);

  for (int kt = 0; kt < 32; ++kt) {
    __syncthreads();
    *(short8v*)((char*)As + sb0) = ap0;
    *(short8v*)((char*)As + sb1) = ap1;
    *(short8v*)((char*)Bs + sb0) = bp0;
    *(short8v*)((char*)Bs + sb1) = bp1;
    __syncthreads();
    if (kt < 31) {
      ap0 = *(const short8v*)(Ag + (kt + 1) * 32);
      ap1 = *(const short8v*)(Ag + 64 * (size_t)D_ + (kt + 1) * 32);
      bp0 = *(const short8v*)(Bg + (kt + 1) * 32);
      bp1 = *(const short8v*)(Bg + 64 * (size_t)D_ + (kt + 1) * 32);
    }
    short8v af[4], bfr[4];
    #pragma unroll
    for (int mi = 0; mi < 4; ++mi) {
      int r = wm * 64 + mi * 16 + frow;
      af[mi] = *(const short8v*)((char*)As + ((r * 64 + fko) ^ ((r & 3) << 4)));
    }
    #pragma unroll
    for (int ni = 0; ni < 4; ++ni) {
      int r = wn * 64 + ni * 16 + frow;
      bfr[ni] = *(const short8v*)((char*)Bs + ((r * 64 + fko) ^ ((r & 3) << 4)));
    }
    #pragma unroll
    for (int mi = 0; mi < 4; ++mi)
      #pragma unroll
      for (int ni = 0; ni < 4; ++ni)
        acc[mi][ni] = __builtin_amdgcn_mfma_f32_16x16x32_bf16(af[mi], bfr[ni], acc[mi][ni], 0, 0, 0);
  }
  // epilogue: +bias, bf16, remap rows to [t][b] and cols to [unit][gate]
  #pragma unroll
  for (int mi = 0; mi < 4; ++mi) {
    #pragma unroll
    for (int ni = 0; ni < 4; ++ni) {
      int col = bn * 128 + wn * 64 + ni * 16 + (l & 15);
      float bv = bias[col];
      int colp = ((col & 1023) << 2) | (col >> 10);   // gate-interleaved
      #pragma unroll
      for (int j = 0; j < 4; ++j) {
        int row = bm * 128 + wm * 64 + mi * 16 + (l >> 4) * 4 + j;
        int zrow = (row & 511) * 32 + (row >> 9);
        Zx[(size_t)zrow * N4_ + colp] = f2bf(acc[mi][ni][j] + bv);
      }
    }
  }
}

// ---------------- persistent LSTM scan ----------------
// 32 WGs x 512 thr (8 waves = 4 K-splits x 2 gate-pairs). WG owns units [wg*32,+32).
// R11 restructure: each wave computes 2 gates per A-fragment read, halving the
// dominant LDS term (A-reads 2048->1024cy; total LDS ~3600->~2500cy/step — R10
// post-mortem found LDS pipe co-dominant with exchange). At 2 waves/SIMD the
// VGPR budget is 256/wave so the 128-VGPR R-fragment set can be truly resident.
// Gate phase: thread owns (row, unit-pair): one 16B Zx load, conflict-free b64
// z-reads, direct u32 publish (no shfl). Exchange protocol = R6 (champion).
__global__ __launch_bounds__(512) __attribute__((amdgpu_waves_per_eu(2, 2)))
void lstm_scan(const u16* __restrict__ Zx,
    const u16* __restrict__ RT, u16* hbuf, float* h_last, u32* flags) {
  __shared__ u16   h_lds[B_ * D_];           // 64 KB, XOR-swizzled rows
  __shared__ float z_lds[4 * 32 * 136];      // 69.6 KB: [ks][row][gate*32+u], stride 136
  int tid = threadIdx.x;
  int wg = blockIdx.x;
  int w = tid >> 6, l = tid & 63;
  int ks = w >> 1, ch = w & 1;               // K-range ks*256..+256; gates {2ch, 2ch+1}
  int bcol = l & 31, hi = l >> 5;

  // preload B fragments (R^T) for BOTH gates of this wave: 2 x 16 x 16B = 128 VGPR
  short8v b0[16], b1[16];
  {
    const u16* R0 = RT + (size_t)((ch * 2 + 0) * 1024 + wg * 32 + bcol) * D_
                  + ks * 256 + hi * 8;
    const u16* R1 = RT + (size_t)((ch * 2 + 1) * 1024 + wg * 32 + bcol) * D_
                  + ks * 256 + hi * 8;
    #pragma unroll
    for (int kt = 0; kt < 16; ++kt) {
      b0[kt] = *(const short8v*)(R0 + kt * 16);
      b1[kt] = *(const short8v*)(R1 + kt * 16);
    }
  }
  #pragma unroll
  for (int kt = 0; kt < 16; ++kt) {
    asm volatile("" : "+v"(b0[kt]));
    asm volatile("" : "+v"(b1[kt]));
  }

  // A-fragment addressing (h in LDS, swizzled)
  int abase = bcol * 2048 + ks * 512 + hi * 16;
  int asw = (bcol & 7) << 4;
  // gate cell: thread -> (row, unit-pair)
  int grow = tid >> 4, gu = (tid & 15) * 2;
  const u16* zx_p = Zx + (size_t)grow * N4_ + (wg * 32 + gu) * 4;  // 8 bf16 = 16B
  int hoff = grow * D_ + wg * 32 + gu;
  float c0 = 0.f, c1 = 0.f;
  const u32* fp = flags + (size_t)(l & 31) * 16;

  #pragma unroll 1
  for (int t = 0; t < T_; ++t) {
    // prefetch both units' 4 gate pre-activations: ONE 16B load (overlaps poll)
    u32x4 zq = *(const u32x4*)(zx_p + (size_t)t * B_ * N4_);
    __builtin_amdgcn_sched_barrier(0);

    // wave0 polls the 32 per-WG flags; raw s_barrier releases the other 7 waves
    if (w == 0) {
      while (true) {
        u32 f = __hip_atomic_load(fp, __ATOMIC_RELAXED, __HIP_MEMORY_SCOPE_AGENT);
        if (__all((int)(f >= (u32)t))) break;
      }
    }
    __builtin_amdgcn_s_barrier();
    __builtin_amdgcn_sched_barrier(0);

    // bulk-load h: 8 x 16B coherent loads per thread (512 thr x 128B = 64KB)
    const char* hbp = (const char*)hbuf + (size_t)(t & 1) * 65536;
    u32x4 hv[8];
    #pragma unroll
    for (int j = 0; j < 8; ++j) {
      const char* p = hbp + j * 8192 + tid * 16;
      asm volatile("global_load_dwordx4 %0, %1, off sc0 sc1"
                   : "=&v"(hv[j]) : "v"(p) : "memory");
    }
    asm volatile("s_waitcnt vmcnt(0)" ::: "memory");
    __builtin_amdgcn_sched_barrier(0);
    #pragma unroll
    for (int j = 0; j < 8; ++j) {
      int byte = j * 8192 + tid * 16;
      int row = byte >> 11;
      *(u32x4*)((char*)h_lds + (byte ^ ((row & 7) << 4))) = hv[j];
    }
    __syncthreads();

    // K-loop: 16 x (1 ds_read_b128 + 2 mfma 32x32x16) — one A-read feeds 2 gates
    f32x16 acc0, acc1;
    #pragma unroll
    for (int i = 0; i < 16; ++i) { acc0[i] = 0.f; acc1[i] = 0.f; }
    #pragma unroll
    for (int kt = 0; kt < 16; ++kt) {
      short8v a = *(const short8v*)((const char*)h_lds + ((abase + kt * 32) ^ asw));
      acc0 = __builtin_amdgcn_mfma_f32_32x32x16_bf16(a, b0[kt], acc0, 0, 0, 0);
      acc1 = __builtin_amdgcn_mfma_f32_32x32x16_bf16(a, b1[kt], acc1, 0, 0, 0);
    }
    // write K-partials: D layout row=(r&3)+8*(r>>2)+4*hi, col=lane&31
    #pragma unroll
    for (int r = 0; r < 16; ++r) {
      int rowD = (r & 3) + 8 * (r >> 2) + 4 * hi;
      z_lds[(ks * 32 + rowD) * 136 + (ch * 2 + 0) * 32 + bcol] = acc0[r];
      z_lds[(ks * 32 + rowD) * 136 + (ch * 2 + 1) * 32 + bcol] = acc1[r];
    }
    __syncthreads();

    // gates: thread owns (grow, gu) and (grow, gu+1); b64 unit-pair reads (conflict-free)
    f32x2 zi, zf, zg, zo;
    zi[0]=zi[1]=zf[0]=zf[1]=zg[0]=zg[1]=zo[0]=zo[1]=0.f;
    #pragma unroll
    for (int kss = 0; kss < 4; ++kss) {
      const f32x2* zr = (const f32x2*)&z_lds[(kss * 32 + grow) * 136 + gu];
      zi += zr[0]; zf += zr[16]; zg += zr[32]; zo += zr[48];
    }
    zi[0] += bf2f((u16)(zq[0] & 0xFFFFu));  zf[0] += bf2f((u16)(zq[0] >> 16));
    zg[0] += bf2f((u16)(zq[1] & 0xFFFFu));  zo[0] += bf2f((u16)(zq[1] >> 16));
    zi[1] += bf2f((u16)(zq[2] & 0xFFFFu));  zf[1] += bf2f((u16)(zq[2] >> 16));
    zg[1] += bf2f((u16)(zq[3] & 0xFFFFu));  zo[1] += bf2f((u16)(zq[3] >> 16));
    float cn0 = sigm(zf[0]) * c0 + sigm(zi[0]) * tanh_fast(zg[0]);
    float hn0 = sigm(zo[0]) * tanh_fast(cn0);
    float cn1 = sigm(zf[1]) * c1 + sigm(zi[1]) * tanh_fast(zg[1]);
    float hn1 = sigm(zo[1]) * tanh_fast(cn1);
    c0 = cn0; c1 = cn1;

    // publish h: direct u32 store (no shfl — thread owns the adjacent unit pair)
    u32 word = (u32)f2bf(hn0) | ((u32)f2bf(hn1) << 16);
    u32* dst = (u32*)(hbuf + (size_t)((t + 1) & 1) * (B_ * D_) + hoff);
    __hip_atomic_store(dst, word, __ATOMIC_RELAXED, __HIP_MEMORY_SCOPE_AGENT);
    if (t == T_ - 1) {
      h_last[hoff]     = hn0;
      h_last[hoff + 1] = hn1;
    }
    // drain all waves' stores, then publish the flag
    __syncthreads();
    if (tid == 0)
      __hip_atomic_store(flags + (size_t)wg * 16, (u32)(t + 1),
                         __ATOMIC_RELAXED, __HIP_MEMORY_SCOPE_AGENT);
  }
}

// ---------------- LN2: out = LN(xn + h_last) fp32 ----------------
__global__ __launch_bounds__(256) void ln2_kernel(const u16* __restrict__ xn,
    const float* __restrict__ h_last, const float* __restrict__ gam,
    const float* __restrict__ bet, float* __restrict__ out) {
  int row = blockIdx.x; int tid = threadIdx.x;
  int bi = row >> 9;
  ushort4v xv = *(const ushort4v*)(xn + (size_t)row * D_ + tid * 4);
  float4 hv = *(const float4*)(h_last + (size_t)bi * D_ + tid * 4);
  float s0 = bf2f(xv.x) + hv.x;
  float s1 = bf2f(xv.y) + hv.y;
  float s2 = bf2f(xv.z) + hv.z;
  float s3 = bf2f(xv.w) + hv.w;
  float s = s0 + s1 + s2 + s3;
  float ss = s0*s0 + s1*s1 + s2*s2 + s3*s3;
  #pragma unroll
  for (int o = 32; o > 0; o >>= 1) { s += __shfl_down(s, o); ss += __shfl_down(ss, o); }
  __shared__ float red[8];
  int w = tid >> 6, l = tid & 63;
  if (l == 0) { red[w] = s; red[4 + w] = ss; }
  __syncthreads();
  s  = red[0] + red[1] + red[2] + red[3];
  ss = red[4] + red[5] + red[6] + red[7];
  float mean = s * (1.f / D_);
  float var  = ss * (1.f / D_) - mean * mean;
  float rstd = rsqrtf(var + 1e-3f);
  float4 g = *(const float4*)(gam + tid * 4);
  float4 b = *(const float4*)(bet + tid * 4);
  float4 o4;
  o4.x = (s0 - mean) * rstd * g.x + b.x;
  o4.y = (s1 - mean) * rstd * g.y + b.y;
  o4.z = (s2 - mean) * rstd * g.z + b.z;
  o4.w = (s3 - mean) * rstd * g.w + b.w;
  *(float4*)(out + (size_t)row * D_ + tid * 4) = o4;
}

extern "C" void kernel_launch(void* const* d_in, const int* in_sizes, int n_in,
                              void* d_out, int out_size, void* d_ws, size_t ws_size,
                              hipStream_t stream) {
  const float* x    = (const float*)d_in[0];
  const float* g1   = (const float*)d_in[1];
  const float* b1   = (const float*)d_in[2];
  const float* Wk   = (const float*)d_in[3];
  const float* Wr   = (const float*)d_in[4];
  const float* bias = (const float*)d_in[5];
  const float* g2   = (const float*)d_in[6];
  const float* b2   = (const float*)d_in[7];
  char* ws = (char*)d_ws;
  u16* xn    = (u16*)(ws + OFF_XN);
  u16* Zx    = (u16*)(ws + OFF_ZX);
  u16* KT    = (u16*)(ws + OFF_KT);
  u16* RT    = (u16*)(ws + OFF_RT);
  u16* hbuf  = (u16*)(ws + OFF_HB);
  u32* flg   = (u32*)(ws + OFF_FLG);
  float* hl  = (float*)(ws + OFF_KT);    // aliases KT (dead after gemm_xk)
  float* out = (float*)d_out;

  init_kernel<<<128, 256, 0, stream>>>((u32*)hbuf, flg);
  ln1_kernel<<<B_ * T_, 256, 0, stream>>>(x, g1, b1, xn);
  transpose_bf16<<<dim3(128, 32), dim3(32, 8), 0, stream>>>(Wk, KT);
  transpose_bf16<<<dim3(128, 32), dim3(32, 8), 0, stream>>>(Wr, RT);
  gemm_xk<<<4096, 256, 0, stream>>>(xn, KT, bias, Zx);
  lstm_scan<<<32, 512, 0, stream>>>(Zx, RT, hbuf, hl, flg);
  ln2_kernel<<<B_ * T_, 256, 0, stream>>>(xn, hl, g2, b2, out);
}

// Round 12
// 1788.269 us; speedup vs baseline: 1.8026x; 1.3125x over previous
//
#include <hip/hip_runtime.h>

typedef unsigned short u16;
typedef unsigned int   u32;
typedef unsigned long long u64;
typedef __attribute__((ext_vector_type(8)))  short  short8v;   // 8 x bf16 (as i16)
typedef __attribute__((ext_vector_type(4)))  float  f32x4;
typedef __attribute__((ext_vector_type(16))) float  f32x16;
typedef __attribute__((ext_vector_type(4)))  unsigned short ushort4v;
typedef __attribute__((ext_vector_type(4)))  u32 u32x4;

#define B_   32
#define T_   512
#define D_   1024
#define N4_  4096
#define NWG  64          // scan workgroups; each owns 16 units

// ---- workspace layout (bytes) ----
#define OFF_XN   0ull                 // xn bf16   [32*512*1024]      33554432
#define OFF_ZX   33554432ull          // Zx bf16   [512][32][1024][4] 134217728  (gate-interleaved)
#define OFF_KT   167772160ull         // kernel^T bf16 [4096][1024]    8388608  (reused as h_last after GEMM)
#define OFF_RT   176160768ull         // recurrent^T bf16 [4096][1024] 8388608
#define OFF_HB   184549376ull         // h double buffer bf16 2*[32][1024] = 131072
#define OFF_FLG  184680448ull         // flags: 64 x 64B-strided u32

__device__ inline u16 f2bf(float f) {
  union { float f; u32 u; } x; x.f = f;
  u32 r = x.u + 0x7FFFu + ((x.u >> 16) & 1u);   // RNE
  return (u16)(r >> 16);
}
__device__ inline float bf2f(u16 h) {
  union { u32 u; float f; } x; x.u = ((u32)h) << 16; return x.f;
}
__device__ inline float sigm(float x) { return 1.f / (1.f + __expf(-x)); }
__device__ inline float tanh_fast(float x) {
  float e = __expf(2.f * x);
  return 1.f - 2.f / (e + 1.f);
}

// ---------------- init: zero h buffers + flags ----------------
__global__ __launch_bounds__(256) void init_kernel(u32* hbuf, u32* flags) {
  int i = blockIdx.x * 256 + threadIdx.x;
  if (i < 32768) hbuf[i] = 0u;       // both parities: 2*32*1024 bf16 = 32768 dwords
  if (i < NWG)   flags[i * 16] = 0u;
}

// ---------------- LN1: x fp32 -> xn bf16 ----------------
__global__ __launch_bounds__(256) void ln1_kernel(const float* __restrict__ x,
    const float* __restrict__ gam, const float* __restrict__ bet, u16* __restrict__ xn) {
  int row = blockIdx.x; int tid = threadIdx.x;
  const float* xr = x + (size_t)row * D_;
  float4 v = *(const float4*)(xr + tid * 4);
  float s  = v.x + v.y + v.z + v.w;
  float ss = v.x*v.x + v.y*v.y + v.z*v.z + v.w*v.w;
  #pragma unroll
  for (int o = 32; o > 0; o >>= 1) { s += __shfl_down(s, o); ss += __shfl_down(ss, o); }
  __shared__ float red[8];
  int w = tid >> 6, l = tid & 63;
  if (l == 0) { red[w] = s; red[4 + w] = ss; }
  __syncthreads();
  s  = red[0] + red[1] + red[2] + red[3];
  ss = red[4] + red[5] + red[6] + red[7];
  float mean = s * (1.f / D_);
  float var  = ss * (1.f / D_) - mean * mean;
  float rstd = rsqrtf(var + 1e-3f);
  float4 g = *(const float4*)(gam + tid * 4);
  float4 b = *(const float4*)(bet + tid * 4);
  ushort4v o4;
  o4.x = f2bf((v.x - mean) * rstd * g.x + b.x);
  o4.y = f2bf((v.y - mean) * rstd * g.y + b.y);
  o4.z = f2bf((v.z - mean) * rstd * g.z + b.z);
  o4.w = f2bf((v.w - mean) * rstd * g.w + b.w);
  *(ushort4v*)(xn + (size_t)row * D_ + tid * 4) = o4;
}

// ---------------- transpose [1024][4096] fp32 -> [4096][1024] bf16 ----------------
__global__ __launch_bounds__(256) void transpose_bf16(const float* __restrict__ W, u16* __restrict__ WT) {
  __shared__ float tile[32][33];
  int c0 = blockIdx.x * 32, r0 = blockIdx.y * 32;
  int tx = threadIdx.x, ty = threadIdx.y;
  #pragma unroll
  for (int i = ty; i < 32; i += 8)
    tile[i][tx] = W[(size_t)(r0 + i) * N4_ + c0 + tx];
  __syncthreads();
  #pragma unroll
  for (int i = ty; i < 32; i += 8)
    WT[(size_t)(c0 + i) * D_ + r0 + tx] = f2bf(tile[tx][i]);
}

// ---------------- GEMM: Zx = xn @ kernel + bias  (gate-interleaved output) ----------------
__global__ __launch_bounds__(256) void gemm_xk(const u16* __restrict__ A, const u16* __restrict__ Bt,
    const float* __restrict__ bias, u16* __restrict__ Zx) {
  __shared__ u16 As[128 * 32];
  __shared__ u16 Bs[128 * 32];
  int tid = threadIdx.x;
  int bm = blockIdx.x >> 5, bn = blockIdx.x & 31;
  int w = tid >> 6, l = tid & 63;
  int srow = tid >> 2, sk = (tid & 3) * 8;        // staging: row j*64+srow, k = sk..sk+8
  const u16* Ag = A  + (size_t)(bm * 128 + srow) * D_ + sk;
  const u16* Bg = Bt + (size_t)(bn * 128 + srow) * D_ + sk;
  int sb0 = (srow * 64 + sk * 2)          ^ ((srow & 3) << 4);
  int sb1 = ((srow + 64) * 64 + sk * 2)   ^ ((srow & 3) << 4);
  int wm = w >> 1, wn = w & 1;
  int frow = l & 15, fko = (l >> 4) * 16;         // fragment k byte offset
  f32x4 acc[4][4];
  #pragma unroll
  for (int mi = 0; mi < 4; ++mi)
    #pragma unroll
    for (int ni = 0; ni < 4; ++ni)
      #pragma unroll
      for (int j = 0; j < 4; ++j) acc[mi][ni][j] = 0.f;

  short8v ap0 = *(const short8v*)(Ag);
  short8v ap1 = *(const short8v*)(Ag + 64 * (size_t)D_);
  short8v bp0 = *(const short8v*)(Bg);
  short8v bp1 = *(const short8v*)(Bg + 64 * (size_t)D_);

  for (int kt = 0; kt < 32; ++kt) {
    __syncthreads();
    *(short8v*)((char*)As + sb0) = ap0;
    *(short8v*)((char*)As + sb1) = ap1;
    *(short8v*)((char*)Bs + sb0) = bp0;
    *(short8v*)((char*)Bs + sb1) = bp1;
    __syncthreads();
    if (kt < 31) {
      ap0 = *(const short8v*)(Ag + (kt + 1) * 32);
      ap1 = *(const short8v*)(Ag + 64 * (size_t)D_ + (kt + 1) * 32);
      bp0 = *(const short8v*)(Bg + (kt + 1) * 32);
      bp1 = *(const short8v*)(Bg + 64 * (size_t)D_ + (kt + 1) * 32);
    }
    short8v af[4], bfr[4];
    #pragma unroll
    for (int mi = 0; mi < 4; ++mi) {
      int r = wm * 64 + mi * 16 + frow;
      af[mi] = *(const short8v*)((char*)As + ((r * 64 + fko) ^ ((r & 3) << 4)));
    }
    #pragma unroll
    for (int ni = 0; ni < 4; ++ni) {
      int r = wn * 64 + ni * 16 + frow;
      bfr[ni] = *(const short8v*)((char*)Bs + ((r * 64 + fko) ^ ((r & 3) << 4)));
    }
    #pragma unroll
    for (int mi = 0; mi < 4; ++mi)
      #pragma unroll
      for (int ni = 0; ni < 4; ++ni)
        acc[mi][ni] = __builtin_amdgcn_mfma_f32_16x16x32_bf16(af[mi], bfr[ni], acc[mi][ni], 0, 0, 0);
  }
  // epilogue: +bias, bf16, remap rows to [t][b] and cols to [unit][gate]
  #pragma unroll
  for (int mi = 0; mi < 4; ++mi) {
    #pragma unroll
    for (int ni = 0; ni < 4; ++ni) {
      int col = bn * 128 + wn * 64 + ni * 16 + (l & 15);
      float bv = bias[col];
      int colp = ((col & 1023) << 2) | (col >> 10);   // gate-interleaved
      #pragma unroll
      for (int j = 0; j < 4; ++j) {
        int row = bm * 128 + wm * 64 + mi * 16 + (l >> 4) * 4 + j;
        int zrow = (row & 511) * 32 + (row >> 9);
        Zx[(size_t)zrow * N4_ + colp] = f2bf(acc[mi][ni][j] + bv);
      }
    }
  }
}

// ---------------- persistent LSTM scan ----------------
// R12: 64 WGs x 512 thr; each WG owns 16 units (64 gate-cols). Halves per-CU R
// streaming (256->128 KB/step) — R11 post-mortem: per-CU L1 operand bandwidth
// (R + h ~ 320KB/step at ~300GB/s ~ 1.07us) is co-dominant and only partially
// overlapped; doubling CUs halves the R term. 8 waves = 4 K-splits x 2 col-halves;
// per wave: 16 x (1 ds_read + 1 mfma 32x32x16). Exchange protocol = R6 champion
// (wave0 flag poll, one flag per lane; 16B sc0/sc1 h loads).
__global__ __launch_bounds__(512) __attribute__((amdgpu_waves_per_eu(2, 2)))
void lstm_scan(const u16* __restrict__ Zx,
    const u16* __restrict__ RT, u16* hbuf, float* h_last, u32* flags) {
  __shared__ u16   h_lds[B_ * D_];           // 64 KB, XOR-swizzled rows
  __shared__ float z_lds[4 * 32 * 68];       // 34.8 KB: [ks][row][64 cols + 4 pad]
  int tid = threadIdx.x;
  int wg = blockIdx.x;
  int w = tid >> 6, l = tid & 63;
  int ks = w >> 1, ch = w & 1;               // K-range ks*256..+256; col-half ch
  int bcol = l & 31, hi = l >> 5;

  // B fragments (R^T): wave col c = ch*32+bcol -> unit u=c>>2, gate g=c&3
  short8v b[16];
  {
    int c = ch * 32 + bcol;
    const u16* Rp = RT + (size_t)((c & 3) * 1024 + wg * 16 + (c >> 2)) * D_
                  + ks * 256 + hi * 8;
    #pragma unroll
    for (int kt = 0; kt < 16; ++kt) b[kt] = *(const short8v*)(Rp + kt * 16);
  }
  #pragma unroll
  for (int kt = 0; kt < 16; ++kt) asm volatile("" : "+v"(b[kt]));

  // A-fragment addressing (h in LDS, swizzled): A-row = l&31 (batch), K slice hi*8
  int abase = (l & 31) * 2048 + ks * 512 + hi * 16;
  int asw = ((l & 31) & 7) << 4;
  // gate cell: thread -> (grow, gu): batch row grow, unit gu (one unit, all 4 gates)
  int grow = tid >> 4, gu = tid & 15;
  const u16* zx_p = Zx + (size_t)grow * N4_ + (wg * 16 + gu) * 4;  // 4 bf16 = 8B
  int hoff = grow * D_ + wg * 16 + gu;
  float c = 0.f;
  const u32* fp = flags + (size_t)l * 16;    // wave0: one flag per lane (64 WGs)

  #pragma unroll 1
  for (int t = 0; t < T_; ++t) {
    // prefetch this unit's 4 gate pre-activations: one 8B load (overlaps poll)
    u64 zq = *(const u64*)(zx_p + (size_t)t * B_ * N4_);
    __builtin_amdgcn_sched_barrier(0);

    // wave0 polls the 64 per-WG flags; raw s_barrier releases the other 7 waves
    if (w == 0) {
      while (true) {
        u32 f = __hip_atomic_load(fp, __ATOMIC_RELAXED, __HIP_MEMORY_SCOPE_AGENT);
        if (__all((int)(f >= (u32)t))) break;
      }
    }
    __builtin_amdgcn_s_barrier();
    __builtin_amdgcn_sched_barrier(0);

    // bulk-load h: 8 x 16B coherent loads per thread (512 thr x 128B = 64KB)
    const char* hbp = (const char*)hbuf + (size_t)(t & 1) * 65536;
    u32x4 hv[8];
    #pragma unroll
    for (int j = 0; j < 8; ++j) {
      const char* p = hbp + j * 8192 + tid * 16;
      asm volatile("global_load_dwordx4 %0, %1, off sc0 sc1"
                   : "=&v"(hv[j]) : "v"(p) : "memory");
    }
    asm volatile("s_waitcnt vmcnt(0)" ::: "memory");
    __builtin_amdgcn_sched_barrier(0);
    #pragma unroll
    for (int j = 0; j < 8; ++j) {
      int byte = j * 8192 + tid * 16;
      int row = byte >> 11;
      *(u32x4*)((char*)h_lds + (byte ^ ((row & 7) << 4))) = hv[j];
    }
    __syncthreads();

    // K-loop: 16 x (1 ds_read_b128 + 1 mfma 32x32x16)
    f32x16 acc;
    #pragma unroll
    for (int i = 0; i < 16; ++i) acc[i] = 0.f;
    #pragma unroll
    for (int kt = 0; kt < 16; ++kt) {
      short8v a = *(const short8v*)((const char*)h_lds + ((abase + kt * 32) ^ asw));
      acc = __builtin_amdgcn_mfma_f32_32x32x16_bf16(a, b[kt], acc, 0, 0, 0);
    }
    // write K-partials: D layout row=(r&3)+8*(r>>2)+4*hi, col=ch*32+bcol
    #pragma unroll
    for (int r = 0; r < 16; ++r) {
      int rowD = (r & 3) + 8 * (r >> 2) + 4 * hi;
      z_lds[(ks * 32 + rowD) * 68 + ch * 32 + bcol] = acc[r];
    }
    __syncthreads();

    // gates: thread owns (grow, gu) — all 4 gates of one unit, f32x4 reads
    float z0 = bf2f((u16)(zq        & 0xFFFFu));
    float z1 = bf2f((u16)((zq >> 16) & 0xFFFFu));
    float z2 = bf2f((u16)((zq >> 32) & 0xFFFFu));
    float z3 = bf2f((u16)((zq >> 48) & 0xFFFFu));
    #pragma unroll
    for (int kss = 0; kss < 4; ++kss) {
      f32x4 zr = *(const f32x4*)&z_lds[(kss * 32 + grow) * 68 + gu * 4];
      z0 += zr[0]; z1 += zr[1]; z2 += zr[2]; z3 += zr[3];
    }
    float cn = sigm(z1) * c + sigm(z0) * tanh_fast(z2);
    float hn = sigm(z3) * tanh_fast(cn);
    c = cn;

    // publish h (pair adjacent units -> u32 agent-scope store)
    u32 hw = (u32)f2bf(hn);
    u32 nb = __shfl_down(hw, 1);
    if (!(gu & 1)) {
      u32* dst = (u32*)(hbuf + (size_t)((t + 1) & 1) * (B_ * D_) + hoff);
      __hip_atomic_store(dst, hw | (nb << 16), __ATOMIC_RELAXED, __HIP_MEMORY_SCOPE_AGENT);
    }
    if (t == T_ - 1) h_last[hoff] = hn;
    // drain all waves' stores, then publish the flag
    __syncthreads();
    if (tid == 0)
      __hip_atomic_store(flags + (size_t)wg * 16, (u32)(t + 1),
                         __ATOMIC_RELAXED, __HIP_MEMORY_SCOPE_AGENT);
  }
}

// ---------------- LN2: out = LN(xn + h_last) fp32 ----------------
__global__ __launch_bounds__(256) void ln2_kernel(const u16* __restrict__ xn,
    const float* __restrict__ h_last, const float* __restrict__ gam,
    const float* __restrict__ bet, float* __restrict__ out) {
  int row = blockIdx.x; int tid = threadIdx.x;
  int bi = row >> 9;
  ushort4v xv = *(const ushort4v*)(xn + (size_t)row * D_ + tid * 4);
  float4 hv = *(const float4*)(h_last + (size_t)bi * D_ + tid * 4);
  float s0 = bf2f(xv.x) + hv.x;
  float s1 = bf2f(xv.y) + hv.y;
  float s2 = bf2f(xv.z) + hv.z;
  float s3 = bf2f(xv.w) + hv.w;
  float s = s0 + s1 + s2 + s3;
  float ss = s0*s0 + s1*s1 + s2*s2 + s3*s3;
  #pragma unroll
  for (int o = 32; o > 0; o >>= 1) { s += __shfl_down(s, o); ss += __shfl_down(ss, o); }
  __shared__ float red[8];
  int w = tid >> 6, l = tid & 63;
  if (l == 0) { red[w] = s; red[4 + w] = ss; }
  __syncthreads();
  s  = red[0] + red[1] + red[2] + red[3];
  ss = red[4] + red[5] + red[6] + red[7];
  float mean = s * (1.f / D_);
  float var  = ss * (1.f / D_) - mean * mean;
  float rstd = rsqrtf(var + 1e-3f);
  float4 g = *(const float4*)(gam + tid * 4);
  float4 b = *(const float4*)(bet + tid * 4);
  float4 o4;
  o4.x = (s0 - mean) * rstd * g.x + b.x;
  o4.y = (s1 - mean) * rstd * g.y + b.y;
  o4.z = (s2 - mean) * rstd * g.z + b.z;
  o4.w = (s3 - mean) * rstd * g.w + b.w;
  *(float4*)(out + (size_t)row * D_ + tid * 4) = o4;
}

extern "C" void kernel_launch(void* const* d_in, const int* in_sizes, int n_in,
                              void* d_out, int out_size, void* d_ws, size_t ws_size,
                              hipStream_t stream) {
  const float* x    = (const float*)d_in[0];
  const float* g1   = (const float*)d_in[1];
  const float* b1   = (const float*)d_in[2];
  const float* Wk   = (const float*)d_in[3];
  const float* Wr   = (const float*)d_in[4];
  const float* bias = (const float*)d_in[5];
  const float* g2   = (const float*)d_in[6];
  const float* b2   = (const float*)d_in[7];
  char* ws = (char*)d_ws;
  u16* xn    = (u16*)(ws + OFF_XN);
  u16* Zx    = (u16*)(ws + OFF_ZX);
  u16* KT    = (u16*)(ws + OFF_KT);
  u16* RT    = (u16*)(ws + OFF_RT);
  u16* hbuf  = (u16*)(ws + OFF_HB);
  u32* flg   = (u32*)(ws + OFF_FLG);
  float* hl  = (float*)(ws + OFF_KT);    // aliases KT (dead after gemm_xk)
  float* out = (float*)d_out;

  init_kernel<<<128, 256, 0, stream>>>((u32*)hbuf, flg);
  ln1_kernel<<<B_ * T_, 256, 0, stream>>>(x, g1, b1, xn);
  transpose_bf16<<<dim3(128, 32), dim3(32, 8), 0, stream>>>(Wk, KT);
  transpose_bf16<<<dim3(128, 32), dim3(32, 8), 0, stream>>>(Wr, RT);
  gemm_xk<<<4096, 256, 0, stream>>>(xn, KT, bias, Zx);
  lstm_scan<<<NWG, 512, 0, stream>>>(Zx, RT, hbuf, hl, flg);
  ln2_kernel<<<B_ * T_, 256, 0, stream>>>(xn, hl, g2, b2, out);
}

// Round 13
// 1642.755 us; speedup vs baseline: 1.9623x; 1.0886x over previous
//
#include <hip/hip_runtime.h>

typedef unsigned short u16;
typedef unsigned int   u32;
typedef unsigned long long u64;
typedef __attribute__((ext_vector_type(8)))  short  short8v;   // 8 x bf16 (as i16)
typedef __attribute__((ext_vector_type(4)))  float  f32x4;
typedef __attribute__((ext_vector_type(16))) float  f32x16;
typedef __attribute__((ext_vector_type(4)))  unsigned short ushort4v;
typedef __attribute__((ext_vector_type(4)))  u32 u32x4;

#define B_   32
#define T_   512
#define D_   1024
#define N4_  4096
#define NWG  128         // scan workgroups; each owns 8 units (32 gate-cols)

// ---- workspace layout (bytes) ----
#define OFF_XN   0ull                 // xn bf16   [32*512*1024]      33554432
#define OFF_ZX   33554432ull          // Zx bf16   [512][32][1024][4] 134217728  (gate-interleaved)
#define OFF_KT   167772160ull         // kernel^T bf16 [4096][1024]    8388608  (reused as h_last after GEMM)
#define OFF_RT   176160768ull         // recurrent^T bf16 [4096][1024] 8388608
#define OFF_HB   184549376ull         // h double buffer bf16 2*[32][1024] = 131072
#define OFF_FLG  184680448ull         // flags: 128 x 64B-strided u32

__device__ inline u16 f2bf(float f) {
  union { float f; u32 u; } x; x.f = f;
  u32 r = x.u + 0x7FFFu + ((x.u >> 16) & 1u);   // RNE
  return (u16)(r >> 16);
}
__device__ inline float bf2f(u16 h) {
  union { u32 u; float f; } x; x.u = ((u32)h) << 16; return x.f;
}
__device__ inline float sigm(float x) { return 1.f / (1.f + __expf(-x)); }
__device__ inline float tanh_fast(float x) {
  float e = __expf(2.f * x);
  return 1.f - 2.f / (e + 1.f);
}

// ---------------- init: zero h buffers + flags ----------------
__global__ __launch_bounds__(256) void init_kernel(u32* hbuf, u32* flags) {
  int i = blockIdx.x * 256 + threadIdx.x;
  if (i < 32768) hbuf[i] = 0u;       // both parities: 2*32*1024 bf16 = 32768 dwords
  if (i < NWG)   flags[i * 16] = 0u;
}

// ---------------- LN1: x fp32 -> xn bf16 ----------------
__global__ __launch_bounds__(256) void ln1_kernel(const float* __restrict__ x,
    const float* __restrict__ gam, const float* __restrict__ bet, u16* __restrict__ xn) {
  int row = blockIdx.x; int tid = threadIdx.x;
  const float* xr = x + (size_t)row * D_;
  float4 v = *(const float4*)(xr + tid * 4);
  float s  = v.x + v.y + v.z + v.w;
  float ss = v.x*v.x + v.y*v.y + v.z*v.z + v.w*v.w;
  #pragma unroll
  for (int o = 32; o > 0; o >>= 1) { s += __shfl_down(s, o); ss += __shfl_down(ss, o); }
  __shared__ float red[8];
  int w = tid >> 6, l = tid & 63;
  if (l == 0) { red[w] = s; red[4 + w] = ss; }
  __syncthreads();
  s  = red[0] + red[1] + red[2] + red[3];
  ss = red[4] + red[5] + red[6] + red[7];
  float mean = s * (1.f / D_);
  float var  = ss * (1.f / D_) - mean * mean;
  float rstd = rsqrtf(var + 1e-3f);
  float4 g = *(const float4*)(gam + tid * 4);
  float4 b = *(const float4*)(bet + tid * 4);
  ushort4v o4;
  o4.x = f2bf((v.x - mean) * rstd * g.x + b.x);
  o4.y = f2bf((v.y - mean) * rstd * g.y + b.y);
  o4.z = f2bf((v.z - mean) * rstd * g.z + b.z);
  o4.w = f2bf((v.w - mean) * rstd * g.w + b.w);
  *(ushort4v*)(xn + (size_t)row * D_ + tid * 4) = o4;
}

// ---------------- transpose [1024][4096] fp32 -> [4096][1024] bf16 ----------------
__global__ __launch_bounds__(256) void transpose_bf16(const float* __restrict__ W, u16* __restrict__ WT) {
  __shared__ float tile[32][33];
  int c0 = blockIdx.x * 32, r0 = blockIdx.y * 32;
  int tx = threadIdx.x, ty = threadIdx.y;
  #pragma unroll
  for (int i = ty; i < 32; i += 8)
    tile[i][tx] = W[(size_t)(r0 + i) * N4_ + c0 + tx];
  __syncthreads();
  #pragma unroll
  for (int i = ty; i < 32; i += 8)
    WT[(size_t)(c0 + i) * D_ + r0 + tx] = f2bf(tile[tx][i]);
}

// ---------------- GEMM: Zx = xn @ kernel + bias  (gate-interleaved output) ----------------
__global__ __launch_bounds__(256) void gemm_xk(const u16* __restrict__ A, const u16* __restrict__ Bt,
    const float* __restrict__ bias, u16* __restrict__ Zx) {
  __shared__ u16 As[128 * 32];
  __shared__ u16 Bs[128 * 32];
  int tid = threadIdx.x;
  int bm = blockIdx.x >> 5, bn = blockIdx.x & 31;
  int w = tid >> 6, l = tid & 63;
  int srow = tid >> 2, sk = (tid & 3) * 8;        // staging: row j*64+srow, k = sk..sk+8
  const u16* Ag = A  + (size_t)(bm * 128 + srow) * D_ + sk;
  const u16* Bg = Bt + (size_t)(bn * 128 + srow) * D_ + sk;
  int sb0 = (srow * 64 + sk * 2)          ^ ((srow & 3) << 4);
  int sb1 = ((srow + 64) * 64 + sk * 2)   ^ ((srow & 3) << 4);
  int wm = w >> 1, wn = w & 1;
  int frow = l & 15, fko = (l >> 4) * 16;         // fragment k byte offset
  f32x4 acc[4][4];
  #pragma unroll
  for (int mi = 0; mi < 4; ++mi)
    #pragma unroll
    for (int ni = 0; ni < 4; ++ni)
      #pragma unroll
      for (int j = 0; j < 4; ++j) acc[mi][ni][j] = 0.f;

  short8v ap0 = *(const short8v*)(Ag);
  short8v ap1 = *(const short8v*)(Ag + 64 * (size_t)D_);
  short8v bp0 = *(const short8v*)(Bg);
  short8v bp1 = *(const short8v*)(Bg + 64 * (size_t)D_);

  for (int kt = 0; kt < 32; ++kt) {
    __syncthreads();
    *(short8v*)((char*)As + sb0) = ap0;
    *(short8v*)((char*)As + sb1) = ap1;
    *(short8v*)((char*)Bs + sb0) = bp0;
    *(short8v*)((char*)Bs + sb1) = bp1;
    __syncthreads();
    if (kt < 31) {
      ap0 = *(const short8v*)(Ag + (kt + 1) * 32);
      ap1 = *(const short8v*)(Ag + 64 * (size_t)D_ + (kt + 1) * 32);
      bp0 = *(const short8v*)(Bg + (kt + 1) * 32);
      bp1 = *(const short8v*)(Bg + 64 * (size_t)D_ + (kt + 1) * 32);
    }
    short8v af[4], bfr[4];
    #pragma unroll
    for (int mi = 0; mi < 4; ++mi) {
      int r = wm * 64 + mi * 16 + frow;
      af[mi] = *(const short8v*)((char*)As + ((r * 64 + fko) ^ ((r & 3) << 4)));
    }
    #pragma unroll
    for (int ni = 0; ni < 4; ++ni) {
      int r = wn * 64 + ni * 16 + frow;
      bfr[ni] = *(const short8v*)((char*)Bs + ((r * 64 + fko) ^ ((r & 3) << 4)));
    }
    #pragma unroll
    for (int mi = 0; mi < 4; ++mi)
      #pragma unroll
      for (int ni = 0; ni < 4; ++ni)
        acc[mi][ni] = __builtin_amdgcn_mfma_f32_16x16x32_bf16(af[mi], bfr[ni], acc[mi][ni], 0, 0, 0);
  }
  // epilogue: +bias, bf16, remap rows to [t][b] and cols to [unit][gate]
  #pragma unroll
  for (int mi = 0; mi < 4; ++mi) {
    #pragma unroll
    for (int ni = 0; ni < 4; ++ni) {
      int col = bn * 128 + wn * 64 + ni * 16 + (l & 15);
      float bv = bias[col];
      int colp = ((col & 1023) << 2) | (col >> 10);   // gate-interleaved
      #pragma unroll
      for (int j = 0; j < 4; ++j) {
        int row = bm * 128 + wm * 64 + mi * 16 + (l >> 4) * 4 + j;
        int zrow = (row & 511) * 32 + (row >> 9);
        Zx[(size_t)zrow * N4_ + colp] = f2bf(acc[mi][ni][j] + bv);
      }
    }
  }
}

// ---------------- persistent LSTM scan ----------------
// R13: 128 WGs x 512 thr; each WG owns 8 units (32 gate-cols). R streaming halves
// again (128->64 KB/CU/step) and LDS drops ~35% (A-reads 64KB, z_lds 36KB) —
// continuing R12's confirmed bandwidth lever. 8 waves = 8 K-splits of 128;
// per wave 8 x (ds_read_b128 + mfma 32x32x16), B-frags only 32 VGPR.
// Gate phase: 256 threads, one unit each (8-ksplit f32x4 sums).
// Exchange = R6 champion protocol; 128 flags, wave0 polls 2 per lane.
__global__ __launch_bounds__(512) __attribute__((amdgpu_waves_per_eu(2, 2)))
void lstm_scan(const u16* __restrict__ Zx,
    const u16* __restrict__ RT, u16* hbuf, float* h_last, u32* flags) {
  __shared__ u16   h_lds[B_ * D_];           // 64 KB, XOR-swizzled rows
  __shared__ float z_lds[8 * 32 * 36];       // 36 KB: [ks][row][32 cols + 4 pad]
  int tid = threadIdx.x;
  int wg = blockIdx.x;
  int w = tid >> 6, l = tid & 63;
  int ks = w;                                // K-range ks*128..+128
  int bcol = l & 31, hi = l >> 5;

  // B fragments (R^T): col c = bcol -> unit wg*8+(c>>2), gate c&3; 8 x 16B = 32 VGPR
  short8v b[8];
  {
    const u16* Rp = RT + (size_t)((bcol & 3) * 1024 + wg * 8 + (bcol >> 2)) * D_
                  + ks * 128 + hi * 8;
    #pragma unroll
    for (int kt = 0; kt < 8; ++kt) b[kt] = *(const short8v*)(Rp + kt * 16);
  }
  #pragma unroll
  for (int kt = 0; kt < 8; ++kt) asm volatile("" : "+v"(b[kt]));

  // A-fragment addressing (h in LDS, swizzled): row = l&31 (batch), K slice hi*8
  int abase = bcol * 2048 + ks * 256 + hi * 16;
  int asw = (bcol & 7) << 4;
  // gate cell (tid < 256): batch row grow, unit gu
  int grow = tid >> 3, gu = tid & 7;
  const u16* zx_p = Zx + (size_t)grow * N4_ + (wg * 8 + gu) * 4;  // 4 bf16 = 8B
  int hoff = grow * D_ + wg * 8 + gu;
  float c = 0.f;
  const u32* fp0 = flags + (size_t)l * 16;          // wave0: 2 flags per lane
  const u32* fp1 = flags + (size_t)(64 + l) * 16;

  #pragma unroll 1
  for (int t = 0; t < T_; ++t) {
    // prefetch this unit's 4 gate pre-activations (tid<256): one 8B load
    u64 zq = 0;
    if (tid < 256) zq = *(const u64*)(zx_p + (size_t)t * B_ * N4_);
    __builtin_amdgcn_sched_barrier(0);

    // wave0 polls the 128 per-WG flags (2 per lane); s_barrier releases the rest
    if (w == 0) {
      while (true) {
        u32 f0 = __hip_atomic_load(fp0, __ATOMIC_RELAXED, __HIP_MEMORY_SCOPE_AGENT);
        u32 f1 = __hip_atomic_load(fp1, __ATOMIC_RELAXED, __HIP_MEMORY_SCOPE_AGENT);
        if (__all((int)(f0 >= (u32)t && f1 >= (u32)t))) break;
      }
    }
    __builtin_amdgcn_s_barrier();
    __builtin_amdgcn_sched_barrier(0);

    // bulk-load h: 8 x 16B coherent loads per thread (512 thr x 128B = 64KB)
    const char* hbp = (const char*)hbuf + (size_t)(t & 1) * 65536;
    u32x4 hv[8];
    #pragma unroll
    for (int j = 0; j < 8; ++j) {
      const char* p = hbp + j * 8192 + tid * 16;
      asm volatile("global_load_dwordx4 %0, %1, off sc0 sc1"
                   : "=&v"(hv[j]) : "v"(p) : "memory");
    }
    asm volatile("s_waitcnt vmcnt(0)" ::: "memory");
    __builtin_amdgcn_sched_barrier(0);
    #pragma unroll
    for (int j = 0; j < 8; ++j) {
      int byte = j * 8192 + tid * 16;
      int row = byte >> 11;
      *(u32x4*)((char*)h_lds + (byte ^ ((row & 7) << 4))) = hv[j];
    }
    __syncthreads();

    // K-loop: 8 x (1 ds_read_b128 + 1 mfma 32x32x16)
    f32x16 acc;
    #pragma unroll
    for (int i = 0; i < 16; ++i) acc[i] = 0.f;
    #pragma unroll
    for (int kt = 0; kt < 8; ++kt) {
      short8v a = *(const short8v*)((const char*)h_lds + ((abase + kt * 32) ^ asw));
      acc = __builtin_amdgcn_mfma_f32_32x32x16_bf16(a, b[kt], acc, 0, 0, 0);
    }
    // write K-partials: D layout row=(r&3)+8*(r>>2)+4*hi, col=bcol
    #pragma unroll
    for (int r = 0; r < 16; ++r) {
      int rowD = (r & 3) + 8 * (r >> 2) + 4 * hi;
      z_lds[(ks * 32 + rowD) * 36 + bcol] = acc[r];
    }
    __syncthreads();

    // gates: 256 threads, one (row, unit) cell each; sum 8 K-splits via f32x4
    if (tid < 256) {
      float z0 = bf2f((u16)(zq        & 0xFFFFu));
      float z1 = bf2f((u16)((zq >> 16) & 0xFFFFu));
      float z2 = bf2f((u16)((zq >> 32) & 0xFFFFu));
      float z3 = bf2f((u16)((zq >> 48) & 0xFFFFu));
      #pragma unroll
      for (int kss = 0; kss < 8; ++kss) {
        f32x4 zr = *(const f32x4*)&z_lds[(kss * 32 + grow) * 36 + gu * 4];
        z0 += zr[0]; z1 += zr[1]; z2 += zr[2]; z3 += zr[3];
      }
      float cn = sigm(z1) * c + sigm(z0) * tanh_fast(z2);
      float hn = sigm(z3) * tanh_fast(cn);
      c = cn;

      // publish h (pair adjacent units -> u32 agent-scope store)
      u32 hw = (u32)f2bf(hn);
      u32 nb = __shfl_down(hw, 1);
      if (!(gu & 1)) {
        u32* dst = (u32*)(hbuf + (size_t)((t + 1) & 1) * (B_ * D_) + hoff);
        __hip_atomic_store(dst, hw | (nb << 16), __ATOMIC_RELAXED, __HIP_MEMORY_SCOPE_AGENT);
      }
      if (t == T_ - 1) h_last[hoff] = hn;
    }
    // drain all waves' stores, then publish the flag
    __syncthreads();
    if (tid == 0)
      __hip_atomic_store(flags + (size_t)wg * 16, (u32)(t + 1),
                         __ATOMIC_RELAXED, __HIP_MEMORY_SCOPE_AGENT);
  }
}

// ---------------- LN2: out = LN(xn + h_last) fp32 ----------------
__global__ __launch_bounds__(256) void ln2_kernel(const u16* __restrict__ xn,
    const float* __restrict__ h_last, const float* __restrict__ gam,
    const float* __restrict__ bet, float* __restrict__ out) {
  int row = blockIdx.x; int tid = threadIdx.x;
  int bi = row >> 9;
  ushort4v xv = *(const ushort4v*)(xn + (size_t)row * D_ + tid * 4);
  float4 hv = *(const float4*)(h_last + (size_t)bi * D_ + tid * 4);
  float s0 = bf2f(xv.x) + hv.x;
  float s1 = bf2f(xv.y) + hv.y;
  float s2 = bf2f(xv.z) + hv.z;
  float s3 = bf2f(xv.w) + hv.w;
  float s = s0 + s1 + s2 + s3;
  float ss = s0*s0 + s1*s1 + s2*s2 + s3*s3;
  #pragma unroll
  for (int o = 32; o > 0; o >>= 1) { s += __shfl_down(s, o); ss += __shfl_down(ss, o); }
  __shared__ float red[8];
  int w = tid >> 6, l = tid & 63;
  if (l == 0) { red[w] = s; red[4 + w] = ss; }
  __syncthreads();
  s  = red[0] + red[1] + red[2] + red[3];
  ss = red[4] + red[5] + red[6] + red[7];
  float mean = s * (1.f / D_);
  float var  = ss * (1.f / D_) - mean * mean;
  float rstd = rsqrtf(var + 1e-3f);
  float4 g = *(const float4*)(gam + tid * 4);
  float4 b = *(const float4*)(bet + tid * 4);
  float4 o4;
  o4.x = (s0 - mean) * rstd * g.x + b.x;
  o4.y = (s1 - mean) * rstd * g.y + b.y;
  o4.z = (s2 - mean) * rstd * g.z + b.z;
  o4.w = (s3 - mean) * rstd * g.w + b.w;
  *(float4*)(out + (size_t)row * D_ + tid * 4) = o4;
}

extern "C" void kernel_launch(void* const* d_in, const int* in_sizes, int n_in,
                              void* d_out, int out_size, void* d_ws, size_t ws_size,
                              hipStream_t stream) {
  const float* x    = (const float*)d_in[0];
  const float* g1   = (const float*)d_in[1];
  const float* b1   = (const float*)d_in[2];
  const float* Wk   = (const float*)d_in[3];
  const float* Wr   = (const float*)d_in[4];
  const float* bias = (const float*)d_in[5];
  const float* g2   = (const float*)d_in[6];
  const float* b2   = (const float*)d_in[7];
  char* ws = (char*)d_ws;
  u16* xn    = (u16*)(ws + OFF_XN);
  u16* Zx    = (u16*)(ws + OFF_ZX);
  u16* KT    = (u16*)(ws + OFF_KT);
  u16* RT    = (u16*)(ws + OFF_RT);
  u16* hbuf  = (u16*)(ws + OFF_HB);
  u32* flg   = (u32*)(ws + OFF_FLG);
  float* hl  = (float*)(ws + OFF_KT);    // aliases KT (dead after gemm_xk)
  float* out = (float*)d_out;

  init_kernel<<<128, 256, 0, stream>>>((u32*)hbuf, flg);
  ln1_kernel<<<B_ * T_, 256, 0, stream>>>(x, g1, b1, xn);
  transpose_bf16<<<dim3(128, 32), dim3(32, 8), 0, stream>>>(Wk, KT);
  transpose_bf16<<<dim3(128, 32), dim3(32, 8), 0, stream>>>(Wr, RT);
  gemm_xk<<<4096, 256, 0, stream>>>(xn, KT, bias, Zx);
  lstm_scan<<<NWG, 512, 0, stream>>>(Zx, RT, hbuf, hl, flg);
  ln2_kernel<<<B_ * T_, 256, 0, stream>>>(xn, hl, g2, b2, out);
}

// Round 14
// 1567.867 us; speedup vs baseline: 2.0560x; 1.0478x over previous
//
#include <hip/hip_runtime.h>

typedef unsigned short u16;
typedef unsigned int   u32;
typedef unsigned long long u64;
typedef __attribute__((ext_vector_type(8)))  short  short8v;   // 8 x bf16 (as i16)
typedef __attribute__((ext_vector_type(4)))  float  f32x4;
typedef __attribute__((ext_vector_type(4)))  unsigned short ushort4v;
typedef __attribute__((ext_vector_type(4)))  u32 u32x4;

#define B_   32
#define T_   512
#define D_   1024
#define N4_  4096
#define NWG  256         // scan WGs: 128 unit-groups (8 units) x 2 batch halves (16 rows)

// ---- workspace layout (bytes) ----
#define OFF_XN   0ull                 // xn bf16   [32*512*1024]      33554432
#define OFF_ZX   33554432ull          // Zx bf16   [512][32][1024][4] 134217728  (gate-interleaved)
#define OFF_KT   167772160ull         // kernel^T bf16 [4096][1024]    8388608  (reused as h_last after GEMM)
#define OFF_RT   176160768ull         // recurrent^T bf16 [4096][1024] 8388608
#define OFF_HB   184549376ull         // h double buffer bf16 2*[32][1024] = 131072
#define OFF_FLG  184680448ull         // flags: 256 x 64B-strided u32

__device__ inline u16 f2bf(float f) {
  union { float f; u32 u; } x; x.f = f;
  u32 r = x.u + 0x7FFFu + ((x.u >> 16) & 1u);   // RNE
  return (u16)(r >> 16);
}
__device__ inline float bf2f(u16 h) {
  union { u32 u; float f; } x; x.u = ((u32)h) << 16; return x.f;
}
__device__ inline float sigm(float x) { return 1.f / (1.f + __expf(-x)); }
__device__ inline float tanh_fast(float x) {
  float e = __expf(2.f * x);
  return 1.f - 2.f / (e + 1.f);
}

// ---------------- init: zero h buffers + flags ----------------
__global__ __launch_bounds__(256) void init_kernel(u32* hbuf, u32* flags) {
  int i = blockIdx.x * 256 + threadIdx.x;
  if (i < 32768) hbuf[i] = 0u;       // both parities: 2*32*1024 bf16 = 32768 dwords
  if (i < NWG)   flags[i * 16] = 0u;
}

// ---------------- LN1: x fp32 -> xn bf16 ----------------
__global__ __launch_bounds__(256) void ln1_kernel(const float* __restrict__ x,
    const float* __restrict__ gam, const float* __restrict__ bet, u16* __restrict__ xn) {
  int row = blockIdx.x; int tid = threadIdx.x;
  const float* xr = x + (size_t)row * D_;
  float4 v = *(const float4*)(xr + tid * 4);
  float s  = v.x + v.y + v.z + v.w;
  float ss = v.x*v.x + v.y*v.y + v.z*v.z + v.w*v.w;
  #pragma unroll
  for (int o = 32; o > 0; o >>= 1) { s += __shfl_down(s, o); ss += __shfl_down(ss, o); }
  __shared__ float red[8];
  int w = tid >> 6, l = tid & 63;
  if (l == 0) { red[w] = s; red[4 + w] = ss; }
  __syncthreads();
  s  = red[0] + red[1] + red[2] + red[3];
  ss = red[4] + red[5] + red[6] + red[7];
  float mean = s * (1.f / D_);
  float var  = ss * (1.f / D_) - mean * mean;
  float rstd = rsqrtf(var + 1e-3f);
  float4 g = *(const float4*)(gam + tid * 4);
  float4 b = *(const float4*)(bet + tid * 4);
  ushort4v o4;
  o4.x = f2bf((v.x - mean) * rstd * g.x + b.x);
  o4.y = f2bf((v.y - mean) * rstd * g.y + b.y);
  o4.z = f2bf((v.z - mean) * rstd * g.z + b.z);
  o4.w = f2bf((v.w - mean) * rstd * g.w + b.w);
  *(ushort4v*)(xn + (size_t)row * D_ + tid * 4) = o4;
}

// ---------------- transpose [1024][4096] fp32 -> [4096][1024] bf16 ----------------
__global__ __launch_bounds__(256) void transpose_bf16(const float* __restrict__ W, u16* __restrict__ WT) {
  __shared__ float tile[32][33];
  int c0 = blockIdx.x * 32, r0 = blockIdx.y * 32;
  int tx = threadIdx.x, ty = threadIdx.y;
  #pragma unroll
  for (int i = ty; i < 32; i += 8)
    tile[i][tx] = W[(size_t)(r0 + i) * N4_ + c0 + tx];
  __syncthreads();
  #pragma unroll
  for (int i = ty; i < 32; i += 8)
    WT[(size_t)(c0 + i) * D_ + r0 + tx] = f2bf(tile[tx][i]);
}

// ---------------- GEMM: Zx = xn @ kernel + bias  (gate-interleaved output) ----------------
__global__ __launch_bounds__(256) void gemm_xk(const u16* __restrict__ A, const u16* __restrict__ Bt,
    const float* __restrict__ bias, u16* __restrict__ Zx) {
  __shared__ u16 As[128 * 32];
  __shared__ u16 Bs[128 * 32];
  int tid = threadIdx.x;
  int bm = blockIdx.x >> 5, bn = blockIdx.x & 31;
  int w = tid >> 6, l = tid & 63;
  int srow = tid >> 2, sk = (tid & 3) * 8;        // staging: row j*64+srow, k = sk..sk+8
  const u16* Ag = A  + (size_t)(bm * 128 + srow) * D_ + sk;
  const u16* Bg = Bt + (size_t)(bn * 128 + srow) * D_ + sk;
  int sb0 = (srow * 64 + sk * 2)          ^ ((srow & 3) << 4);
  int sb1 = ((srow + 64) * 64 + sk * 2)   ^ ((srow & 3) << 4);
  int wm = w >> 1, wn = w & 1;
  int frow = l & 15, fko = (l >> 4) * 16;         // fragment k byte offset
  f32x4 acc[4][4];
  #pragma unroll
  for (int mi = 0; mi < 4; ++mi)
    #pragma unroll
    for (int ni = 0; ni < 4; ++ni)
      #pragma unroll
      for (int j = 0; j < 4; ++j) acc[mi][ni][j] = 0.f;

  short8v ap0 = *(const short8v*)(Ag);
  short8v ap1 = *(const short8v*)(Ag + 64 * (size_t)D_);
  short8v bp0 = *(const short8v*)(Bg);
  short8v bp1 = *(const short8v*)(Bg + 64 * (size_t)D_);

  for (int kt = 0; kt < 32; ++kt) {
    __syncthreads();
    *(short8v*)((char*)As + sb0) = ap0;
    *(short8v*)((char*)As + sb1) = ap1;
    *(short8v*)((char*)Bs + sb0) = bp0;
    *(short8v*)((char*)Bs + sb1) = bp1;
    __syncthreads();
    if (kt < 31) {
      ap0 = *(const short8v*)(Ag + (kt + 1) * 32);
      ap1 = *(const short8v*)(Ag + 64 * (size_t)D_ + (kt + 1) * 32);
      bp0 = *(const short8v*)(Bg + (kt + 1) * 32);
      bp1 = *(const short8v*)(Bg + 64 * (size_t)D_ + (kt + 1) * 32);
    }
    short8v af[4], bfr[4];
    #pragma unroll
    for (int mi = 0; mi < 4; ++mi) {
      int r = wm * 64 + mi * 16 + frow;
      af[mi] = *(const short8v*)((char*)As + ((r * 64 + fko) ^ ((r & 3) << 4)));
    }
    #pragma unroll
    for (int ni = 0; ni < 4; ++ni) {
      int r = wn * 64 + ni * 16 + frow;
      bfr[ni] = *(const short8v*)((char*)Bs + ((r * 64 + fko) ^ ((r & 3) << 4)));
    }
    #pragma unroll
    for (int mi = 0; mi < 4; ++mi)
      #pragma unroll
      for (int ni = 0; ni < 4; ++ni)
        acc[mi][ni] = __builtin_amdgcn_mfma_f32_16x16x32_bf16(af[mi], bfr[ni], acc[mi][ni], 0, 0, 0);
  }
  // epilogue: +bias, bf16, remap rows to [t][b] and cols to [unit][gate]
  #pragma unroll
  for (int mi = 0; mi < 4; ++mi) {
    #pragma unroll
    for (int ni = 0; ni < 4; ++ni) {
      int col = bn * 128 + wn * 64 + ni * 16 + (l & 15);
      float bv = bias[col];
      int colp = ((col & 1023) << 2) | (col >> 10);   // gate-interleaved
      #pragma unroll
      for (int j = 0; j < 4; ++j) {
        int row = bm * 128 + wm * 64 + mi * 16 + (l >> 4) * 4 + j;
        int zrow = (row & 511) * 32 + (row >> 9);
        Zx[(size_t)zrow * N4_ + colp] = f2bf(acc[mi][ni][j] + bv);
      }
    }
  }
}

// ---------------- persistent LSTM scan ----------------
// R14: 256 WGs x 512 thr = 128 unit-groups (8 units, 32 gate-cols) x 2 batch
// halves (16 rows). Batch-split halves the h-load (64->32 KB/CU/step) and all
// LDS phases — R12/R13 confirmed per-CU streaming is the lever; h was the
// largest remaining term. MFMA 16x16x32 (M=16 batch rows); 8 waves = 8 K-splits
// of 128; per wave 4 K-steps x 2 col-halves. Exchange = champion protocol
// (wave0 polls 256 flags = 4/lane; 16B sc0/sc1 h loads; 2 barriers/step).
__global__ __launch_bounds__(512) __attribute__((amdgpu_waves_per_eu(2, 2)))
void lstm_scan(const u16* __restrict__ Zx,
    const u16* __restrict__ RT, u16* hbuf, float* h_last, u32* flags) {
  __shared__ u16   h_lds[16 * D_];           // 32 KB, XOR-swizzled rows (16 batch rows)
  __shared__ float z_lds[8 * 16 * 36];       // 18 KB: [ks][row16][32 cols + 4 pad]
  int tid = threadIdx.x;
  int wg = blockIdx.x;
  int ug = wg >> 1, bh = wg & 1;             // unit-group, batch half
  int w = tid >> 6, l = tid & 63;
  int ks = w;                                // K-range ks*128..+128
  int fr = l & 15, hi = l >> 4;              // fragment row/col 0..15, k-quarter 0..3

  // B fragments (R^T): col c = ch*16+fr -> unit ug*8+(c>>2), gate c&3
  // b[kt][ch]: kt = K-step (32 elems), ch = col half; 8 x 16B = 32 VGPR
  short8v b[4][2];
  #pragma unroll
  for (int ch = 0; ch < 2; ++ch) {
    int c = ch * 16 + fr;
    const u16* Rp = RT + (size_t)((c & 3) * 1024 + ug * 8 + (c >> 2)) * D_
                  + ks * 128 + hi * 8;
    #pragma unroll
    for (int kt = 0; kt < 4; ++kt) b[kt][ch] = *(const short8v*)(Rp + kt * 32);
  }
  #pragma unroll
  for (int kt = 0; kt < 4; ++kt) {
    asm volatile("" : "+v"(b[kt][0]));
    asm volatile("" : "+v"(b[kt][1]));
  }

  // A-fragment addressing (h in LDS, swizzled): row = fr (local batch), k-quarter hi
  int abase = fr * 2048 + ks * 256 + hi * 16;
  int asw = (fr & 7) << 4;
  // gate cell (tid < 128): local batch row grow (0..15), unit gu (0..7)
  int grow = tid >> 3, gu = tid & 7;
  const u16* zx_p = Zx + (size_t)(bh * 16 + grow) * N4_ + (ug * 8 + gu) * 4;
  int hoff = (bh * 16 + grow) * D_ + ug * 8 + gu;
  float c = 0.f;
  const u32* fp0 = flags + (size_t)l * 16;           // wave0: 4 flags per lane
  const u32* fp1 = flags + (size_t)(64 + l) * 16;
  const u32* fp2 = flags + (size_t)(128 + l) * 16;
  const u32* fp3 = flags + (size_t)(192 + l) * 16;

  #pragma unroll 1
  for (int t = 0; t < T_; ++t) {
    // prefetch this unit's 4 gate pre-activations (tid<128): one 8B load
    u64 zq = 0;
    if (tid < 128) zq = *(const u64*)(zx_p + (size_t)t * B_ * N4_);
    __builtin_amdgcn_sched_barrier(0);

    // wave0 polls the 256 per-WG flags (4 per lane); s_barrier releases the rest
    if (w == 0) {
      while (true) {
        u32 f0 = __hip_atomic_load(fp0, __ATOMIC_RELAXED, __HIP_MEMORY_SCOPE_AGENT);
        u32 f1 = __hip_atomic_load(fp1, __ATOMIC_RELAXED, __HIP_MEMORY_SCOPE_AGENT);
        u32 f2 = __hip_atomic_load(fp2, __ATOMIC_RELAXED, __HIP_MEMORY_SCOPE_AGENT);
        u32 f3 = __hip_atomic_load(fp3, __ATOMIC_RELAXED, __HIP_MEMORY_SCOPE_AGENT);
        u32 t32 = (u32)t;
        if (__all((int)(f0 >= t32 && f1 >= t32 && f2 >= t32 && f3 >= t32))) break;
      }
    }
    __builtin_amdgcn_s_barrier();
    __builtin_amdgcn_sched_barrier(0);

    // bulk-load h for our 16 batch rows: 4 x 16B per thread (512 thr x 64B = 32KB)
    const char* hbp = (const char*)hbuf + (size_t)(t & 1) * 65536 + (size_t)bh * 32768;
    u32x4 hv[4];
    #pragma unroll
    for (int j = 0; j < 4; ++j) {
      const char* p = hbp + j * 8192 + tid * 16;
      asm volatile("global_load_dwordx4 %0, %1, off sc0 sc1"
                   : "=&v"(hv[j]) : "v"(p) : "memory");
    }
    asm volatile("s_waitcnt vmcnt(0)" ::: "memory");
    __builtin_amdgcn_sched_barrier(0);
    #pragma unroll
    for (int j = 0; j < 4; ++j) {
      int byte = j * 8192 + tid * 16;
      int row = byte >> 11;
      *(u32x4*)((char*)h_lds + (byte ^ ((row & 7) << 4))) = hv[j];
    }
    __syncthreads();

    // K-loop: 4 K-steps x (1 ds_read_b128 + 2 mfma 16x16x32)
    f32x4 acc0, acc1;
    #pragma unroll
    for (int i = 0; i < 4; ++i) { acc0[i] = 0.f; acc1[i] = 0.f; }
    #pragma unroll
    for (int kt = 0; kt < 4; ++kt) {
      short8v a = *(const short8v*)((const char*)h_lds + ((abase + kt * 64) ^ asw));
      acc0 = __builtin_amdgcn_mfma_f32_16x16x32_bf16(a, b[kt][0], acc0, 0, 0, 0);
      acc1 = __builtin_amdgcn_mfma_f32_16x16x32_bf16(a, b[kt][1], acc1, 0, 0, 0);
    }
    // write K-partials: 16x16 D layout row=(l>>4)*4+j, col=l&15
    #pragma unroll
    for (int j = 0; j < 4; ++j) {
      int rowD = hi * 4 + j;
      z_lds[(ks * 16 + rowD) * 36 + fr]      = acc0[j];
      z_lds[(ks * 16 + rowD) * 36 + 16 + fr] = acc1[j];
    }
    __syncthreads();

    // gates: 128 threads, one (row, unit) cell each; sum 8 K-splits via f32x4
    if (tid < 128) {
      float z0 = bf2f((u16)(zq        & 0xFFFFu));
      float z1 = bf2f((u16)((zq >> 16) & 0xFFFFu));
      float z2 = bf2f((u16)((zq >> 32) & 0xFFFFu));
      float z3 = bf2f((u16)((zq >> 48) & 0xFFFFu));
      #pragma unroll
      for (int kss = 0; kss < 8; ++kss) {
        f32x4 zr = *(const f32x4*)&z_lds[(kss * 16 + grow) * 36 + gu * 4];
        z0 += zr[0]; z1 += zr[1]; z2 += zr[2]; z3 += zr[3];
      }
      float cn = sigm(z1) * c + sigm(z0) * tanh_fast(z2);
      float hn = sigm(z3) * tanh_fast(cn);
      c = cn;

      // publish h (pair adjacent units -> u32 agent-scope store)
      u32 hw = (u32)f2bf(hn);
      u32 nb = __shfl_down(hw, 1);
      if (!(gu & 1)) {
        u32* dst = (u32*)(hbuf + (size_t)((t + 1) & 1) * (B_ * D_) + hoff);
        __hip_atomic_store(dst, hw | (nb << 16), __ATOMIC_RELAXED, __HIP_MEMORY_SCOPE_AGENT);
      }
      if (t == T_ - 1) h_last[hoff] = hn;
    }
    // drain all waves' stores, then publish the flag
    __syncthreads();
    if (tid == 0)
      __hip_atomic_store(flags + (size_t)wg * 16, (u32)(t + 1),
                         __ATOMIC_RELAXED, __HIP_MEMORY_SCOPE_AGENT);
  }
}

// ---------------- LN2: out = LN(xn + h_last) fp32 ----------------
__global__ __launch_bounds__(256) void ln2_kernel(const u16* __restrict__ xn,
    const float* __restrict__ h_last, const float* __restrict__ gam,
    const float* __restrict__ bet, float* __restrict__ out) {
  int row = blockIdx.x; int tid = threadIdx.x;
  int bi = row >> 9;
  ushort4v xv = *(const ushort4v*)(xn + (size_t)row * D_ + tid * 4);
  float4 hv = *(const float4*)(h_last + (size_t)bi * D_ + tid * 4);
  float s0 = bf2f(xv.x) + hv.x;
  float s1 = bf2f(xv.y) + hv.y;
  float s2 = bf2f(xv.z) + hv.z;
  float s3 = bf2f(xv.w) + hv.w;
  float s = s0 + s1 + s2 + s3;
  float ss = s0*s0 + s1*s1 + s2*s2 + s3*s3;
  #pragma unroll
  for (int o = 32; o > 0; o >>= 1) { s += __shfl_down(s, o); ss += __shfl_down(ss, o); }
  __shared__ float red[8];
  int w = tid >> 6, l = tid & 63;
  if (l == 0) { red[w] = s; red[4 + w] = ss; }
  __syncthreads();
  s  = red[0] + red[1] + red[2] + red[3];
  ss = red[4] + red[5] + red[6] + red[7];
  float mean = s * (1.f / D_);
  float var  = ss * (1.f / D_) - mean * mean;
  float rstd = rsqrtf(var + 1e-3f);
  float4 g = *(const float4*)(gam + tid * 4);
  float4 b = *(const float4*)(bet + tid * 4);
  float4 o4;
  o4.x = (s0 - mean) * rstd * g.x + b.x;
  o4.y = (s1 - mean) * rstd * g.y + b.y;
  o4.z = (s2 - mean) * rstd * g.z + b.z;
  o4.w = (s3 - mean) * rstd * g.w + b.w;
  *(float4*)(out + (size_t)row * D_ + tid * 4) = o4;
}

extern "C" void kernel_launch(void* const* d_in, const int* in_sizes, int n_in,
                              void* d_out, int out_size, void* d_ws, size_t ws_size,
                              hipStream_t stream) {
  const float* x    = (const float*)d_in[0];
  const float* g1   = (const float*)d_in[1];
  const float* b1   = (const float*)d_in[2];
  const float* Wk   = (const float*)d_in[3];
  const float* Wr   = (const float*)d_in[4];
  const float* bias = (const float*)d_in[5];
  const float* g2   = (const float*)d_in[6];
  const float* b2   = (const float*)d_in[7];
  char* ws = (char*)d_ws;
  u16* xn    = (u16*)(ws + OFF_XN);
  u16* Zx    = (u16*)(ws + OFF_ZX);
  u16* KT    = (u16*)(ws + OFF_KT);
  u16* RT    = (u16*)(ws + OFF_RT);
  u16* hbuf  = (u16*)(ws + OFF_HB);
  u32* flg   = (u32*)(ws + OFF_FLG);
  float* hl  = (float*)(ws + OFF_KT);    // aliases KT (dead after gemm_xk)
  float* out = (float*)d_out;

  init_kernel<<<128, 256, 0, stream>>>((u32*)hbuf, flg);
  ln1_kernel<<<B_ * T_, 256, 0, stream>>>(x, g1, b1, xn);
  transpose_bf16<<<dim3(128, 32), dim3(32, 8), 0, stream>>>(Wk, KT);
  transpose_bf16<<<dim3(128, 32), dim3(32, 8), 0, stream>>>(Wr, RT);
  gemm_xk<<<4096, 256, 0, stream>>>(xn, KT, bias, Zx);
  lstm_scan<<<NWG, 512, 0, stream>>>(Zx, RT, hbuf, hl, flg);
  ln2_kernel<<<B_ * T_, 256, 0, stream>>>(xn, hl, g2, b2, out);
}